// Round 5
// baseline (808.426 us; speedup 1.0000x reference)
//
#include <hip/hip_runtime.h>
#include <hip/hip_bf16.h>
#include <stdint.h>

#define N_B 4
#define SEQ 2048
#define NH 16
#define ED 128      // expanded feature dim per head
#define EMB 1024
#define FCK 2048    // NH*ED

typedef float f32x4 __attribute__((ext_vector_type(4)));
typedef _Float16 f16x8 __attribute__((ext_vector_type(8)));
typedef _Float16 f16x4 __attribute__((ext_vector_type(4)));

__device__ __forceinline__ void gload16(const void* g, void* l) {
    __builtin_amdgcn_global_load_lds(
        (const __attribute__((address_space(1))) uint32_t*)(g),
        (__attribute__((address_space(3))) uint32_t*)(l), 16, 0, 0);
}

// ---------------------------------------------------------------------------
// Kernel 1: feature map. One wave per (n,s); 16 heads = 16 MFMA rows.
// z via hi/lo fp16 split of x and fm_w (3-term) -> ~fp32-accurate z.
// Outputs (all [nh][s][128] fp16, coalesced-ish writes):
//   qf (scaled 1/32), kf, vf. V transpose happens in vtrans_kernel.
// ---------------------------------------------------------------------------
__global__ __launch_bounds__(256) void fmap_kernel(
    const float* __restrict__ vals, const float* __restrict__ keys,
    const float* __restrict__ qry,  const float* __restrict__ fmw,
    const float* __restrict__ fmb,
    _Float16* __restrict__ qf, _Float16* __restrict__ kf,
    _Float16* __restrict__ vf)
{
    const int lane = threadIdx.x & 63;
    const int w = threadIdx.x >> 6;
    const int t = blockIdx.x * 4 + w;      // (n*SEQ + s)
    const int n = t >> 11;
    const int s = t & 2047;
    const int r = lane & 15;
    const int g = lane >> 4;

    f16x8 whf[4][2], wlf[4][2];
    #pragma unroll
    for (int te = 0; te < 4; ++te) {
      #pragma unroll
      for (int j = 0; j < 2; ++j) {
        const float* p = fmw + (te*16 + r)*64 + j*32 + 8*g;
        #pragma unroll
        for (int i = 0; i < 8; ++i) {
            float wv = p[i];
            _Float16 hi = (_Float16)wv;
            whf[te][j][i] = hi;
            wlf[te][j][i] = (_Float16)(wv - (float)hi);
        }
      }
    }
    float bias[4];
    #pragma unroll
    for (int te = 0; te < 4; ++te) bias[te] = fmb[te*16 + r];

    const long rowoff = ((long)t*16 + r) * 64;
    const float* srcs[3] = {qry, keys, vals};
    #pragma unroll
    for (int tens = 0; tens < 3; ++tens) {
        const float* src = srcs[tens] + rowoff;
        f16x8 ah[2], al[2];
        #pragma unroll
        for (int j = 0; j < 2; ++j) {
            #pragma unroll
            for (int i = 0; i < 8; ++i) {
                float x = src[j*32 + 8*g + i];
                _Float16 hi = (_Float16)x;
                ah[j][i] = hi;
                al[j][i] = (_Float16)(x - (float)hi);
            }
        }
        #pragma unroll
        for (int te = 0; te < 4; ++te) {
            f32x4 c = (f32x4){0.f,0.f,0.f,0.f};
            c = __builtin_amdgcn_mfma_f32_16x16x32_f16(ah[0], whf[te][0], c, 0, 0, 0);
            c = __builtin_amdgcn_mfma_f32_16x16x32_f16(ah[1], whf[te][1], c, 0, 0, 0);
            c = __builtin_amdgcn_mfma_f32_16x16x32_f16(ah[0], wlf[te][0], c, 0, 0, 0);
            c = __builtin_amdgcn_mfma_f32_16x16x32_f16(ah[1], wlf[te][1], c, 0, 0, 0);
            c = __builtin_amdgcn_mfma_f32_16x16x32_f16(al[0], whf[te][0], c, 0, 0, 0);
            c = __builtin_amdgcn_mfma_f32_16x16x32_f16(al[1], whf[te][1], c, 0, 0, 0);
            #pragma unroll
            for (int i = 0; i < 4; ++i) {
                float z = c[i] + bias[te];
                float ep = __expf(z), en = __expf(-z);
                int hh = 4*g + i;
                int e = te*16 + r;
                long base = (((long)n*NH + hh)*SEQ + s)*ED;
                if (tens == 0) {
                    qf[base + e]      = (_Float16)(ep * 0.03125f);  // fold 1/sqrt(1024)
                    qf[base + 64 + e] = (_Float16)(en * 0.03125f);
                } else if (tens == 1) {
                    kf[base + e]      = (_Float16)ep;
                    kf[base + 64 + e] = (_Float16)en;
                } else {
                    vf[base + e]      = (_Float16)ep;
                    vf[base + 64 + e] = (_Float16)en;
                }
            }
        }
    }
}

// ---------------------------------------------------------------------------
// Kernel 1b: vt[nh][e][s] = vf[nh][s][e] via 64x64 LDS tiles (both sides
// coalesced). 64 MB traffic total.
// ---------------------------------------------------------------------------
__global__ __launch_bounds__(256) void vtrans_kernel(
    const _Float16* __restrict__ vf, _Float16* __restrict__ vt)
{
    __shared__ _Float16 tile[64][72];
    const int b = blockIdx.x;          // nh*64 + st*2 + et
    const int et = b & 1;
    const int st = (b >> 1) & 31;
    const int nh = b >> 6;
    const _Float16* src = vf + ((long)nh*SEQ + st*64)*ED + et*64;
    const int col4 = (threadIdx.x & 15) * 4;
    const int row0 = threadIdx.x >> 4;
    #pragma unroll
    for (int j = 0; j < 4; ++j) {
        int row = row0 + j*16;
        *(f16x4*)&tile[row][col4] = *(const f16x4*)(src + (long)row*ED + col4);
    }
    __syncthreads();
    _Float16* dst = vt + ((long)nh*ED + et*64)*SEQ + st*64;
    const int erow = threadIdx.x >> 2;
    const int sc0 = (threadIdx.x & 3) * 16;
    f16x8 o0, o1;
    #pragma unroll
    for (int i = 0; i < 8; ++i) o0[i] = tile[sc0 + i][erow];
    #pragma unroll
    for (int i = 0; i < 8; ++i) o1[i] = tile[sc0 + 8 + i][erow];
    *(f16x8*)(dst + (long)erow*SEQ + sc0) = o0;
    *(f16x8*)(dst + (long)erow*SEQ + sc0 + 8) = o1;
}

// ---------------------------------------------------------------------------
// Kernel 2: fc_w fp32 -> fp16
// ---------------------------------------------------------------------------
__global__ __launch_bounds__(256) void cvt_kernel(
    const float* __restrict__ src, _Float16* __restrict__ dst)
{
    long i = ((long)blockIdx.x*256 + threadIdx.x)*8;
    f16x8 o;
    #pragma unroll
    for (int j = 0; j < 8; ++j) o[j] = (_Float16)src[i + j];
    *(f16x8*)(dst + i) = o;
}

// ---------------------------------------------------------------------------
// Kernel 3: flash attention. 512-thread blocks (8 waves) share one KVBLK=64
// LDS-staged K/V stream (double-buffered, global_load_lds, XOR chunk
// swizzle). Wave w owns 32 q-rows; block owns 256 q-rows of one (n,h).
// XCD-swizzled so each XCD keeps 8 (n,h) K/V streams in its L2.
// Defer-rescale (THR=8, per-lane max, __any guard). setprio around MFMA.
// ---------------------------------------------------------------------------
__global__ __launch_bounds__(512, 4) void attn_kernel(
    const _Float16* __restrict__ qf,
    const _Float16* __restrict__ kf,
    const _Float16* __restrict__ vt,
    _Float16* __restrict__ ob)
{
    __shared__ char smem[65536];
    const int lane = threadIdx.x & 63;
    const int w = threadIdx.x >> 6;              // 0..7
    const int orig = blockIdx.x;                 // 512 blocks
    const int b = ((orig & 7) << 6) | (orig >> 3);  // bijective XCD swizzle
    const int nh = b >> 3;
    const int n = nh >> 4, h = nh & 15;
    const int qt = (b & 7)*8 + w;                // 0..63, 32 q-rows each
    const int r = lane & 15, g = lane >> 4;

    const _Float16* qb = qf + (long)nh*SEQ*ED;
    const char* kg = (const char*)(kf + (long)nh*SEQ*ED);   // row = 256 B
    const char* vg = (const char*)(vt + (long)nh*ED*SEQ);   // row = SEQ*2 B

    f16x8 qfr[2][4];
    #pragma unroll
    for (int u = 0; u < 2; ++u) {
      #pragma unroll
      for (int j = 0; j < 4; ++j)
        qfr[u][j] = *(const f16x8*)(qb + (long)(qt*32 + u*16 + r)*ED + j*32 + 8*g);
    }

    // cooperative stage of one 64-row K/V tile; 4 gloads per wave
    auto stage = [&](int kt, int bsel) {
        char* Kl = smem + bsel*32768;
        char* Vl = Kl + 16384;
        const char* kts = kg + (long)kt*64*256;
        const char* vts = vg + (long)kt*64*2;
        #pragma unroll
        for (int i = 0; i < 2; ++i) {                 // K rows [w*8, w*8+8)
            int row = w*8 + i*4 + (lane>>4);
            int c = (lane&15) ^ (row&15);
            gload16(kts + (long)row*256 + c*16, Kl + (w*8 + i*4)*256);
        }
        #pragma unroll
        for (int i = 0; i < 2; ++i) {                 // V rows [w*16, w*16+16)
            int row = w*16 + i*8 + (lane>>3);
            int c = (lane&7) ^ (row&7);
            gload16(vts + (long)row*(SEQ*2) + c*16, Vl + (w*16 + i*8)*128);
        }
    };

    f32x4 acc[2][8];
    #pragma unroll
    for (int u = 0; u < 2; ++u)
      #pragma unroll
      for (int v2 = 0; v2 < 8; ++v2) acc[u][v2] = (f32x4){0.f,0.f,0.f,0.f};
    float mrun[2] = {-1e30f, -1e30f};
    float lrun[2] = {0.f, 0.f};

    stage(0, 0);
    __syncthreads();

    for (int kt = 0; kt < SEQ/64; ++kt) {
        const int cur = kt & 1;
        if (kt + 1 < SEQ/64) stage(kt + 1, cur ^ 1);
        const _Float16* Kl = (const _Float16*)(smem + cur*32768);
        const _Float16* Vl = Kl + 8192;

        // QK^T for 64 columns
        f32x4 sc4[2][4];
        #pragma unroll
        for (int c4 = 0; c4 < 4; ++c4) {
            f16x8 khf[4];
            #pragma unroll
            for (int j = 0; j < 4; ++j)
                khf[j] = *(const f16x8*)(Kl + (c4*16 + r)*128 + (((j*4 + g) ^ r) << 3));
            __builtin_amdgcn_s_setprio(1);
            #pragma unroll
            for (int u = 0; u < 2; ++u) {
                f32x4 s = (f32x4){0.f,0.f,0.f,0.f};
                #pragma unroll
                for (int j = 0; j < 4; ++j)
                    s = __builtin_amdgcn_mfma_f32_16x16x32_f16(khf[j], qfr[u][j], s, 0, 0, 0);
                sc4[u][c4] = s;
            }
            __builtin_amdgcn_s_setprio(0);
        }

        // online softmax with defer-rescale (per-lane running max per q-row)
        f16x4 pbv[2][4];
        #pragma unroll
        for (int u = 0; u < 2; ++u) {
            float mx = sc4[u][0][0];
            #pragma unroll
            for (int c4 = 0; c4 < 4; ++c4)
                #pragma unroll
                for (int i2 = 0; i2 < 4; ++i2) mx = fmaxf(mx, sc4[u][c4][i2]);
            mx = fmaxf(mx, __shfl_xor(mx, 16, 64));
            mx = fmaxf(mx, __shfl_xor(mx, 32, 64));   // uniform over each q-row's 4 lanes
            if (__any(mx > mrun[u] + 8.0f)) {
                float mnew = fmaxf(mrun[u], mx);
                float corr = __expf(mrun[u] - mnew);
                lrun[u] *= corr;
                #pragma unroll
                for (int v2 = 0; v2 < 8; ++v2) {
                    acc[u][v2][0] *= corr; acc[u][v2][1] *= corr;
                    acc[u][v2][2] *= corr; acc[u][v2][3] *= corr;
                }
                mrun[u] = mnew;
            }
            float rs = 0.f;
            #pragma unroll
            for (int c4 = 0; c4 < 4; ++c4) {
                f16x4 p;
                #pragma unroll
                for (int i2 = 0; i2 < 4; ++i2) {
                    float pv = __expf(sc4[u][c4][i2] - mrun[u]);   // <= e^8
                    p[i2] = (_Float16)pv;
                    rs += (float)p[i2];            // denom from rounded p
                }
                pbv[u][c4] = p;
            }
            rs += __shfl_xor(rs, 16, 64);
            rs += __shfl_xor(rs, 32, 64);
            lrun[u] += rs;
        }

        // PV: 64-col tile in 4 sub-chunks of 16
        #pragma unroll
        for (int kq = 0; kq < 4; ++kq) {
            f16x4 vfr[8];
            #pragma unroll
            for (int v2 = 0; v2 < 8; ++v2)
                vfr[v2] = *(const f16x4*)(Vl + (v2*16 + r)*64 +
                            ((((kq*2 + (g>>1)) ^ (r&7)) << 3) + ((g&1) << 2)));
            __builtin_amdgcn_s_setprio(1);
            #pragma unroll
            for (int u = 0; u < 2; ++u)
                #pragma unroll
                for (int v2 = 0; v2 < 8; ++v2)
                    acc[u][v2] = __builtin_amdgcn_mfma_f32_16x16x16f16(vfr[v2], pbv[u][kq], acc[u][v2], 0, 0, 0);
            __builtin_amdgcn_s_setprio(0);
        }
        __syncthreads();   // drains vmcnt (stage kt+1 done) + protects buffers
    }

    #pragma unroll
    for (int u = 0; u < 2; ++u) {
        float inv = 1.0f / lrun[u];
        int q = qt*32 + u*16 + r;
        long base = ((long)n*SEQ + q)*FCK + h*ED;
        #pragma unroll
        for (int v2 = 0; v2 < 8; ++v2) {
            f16x4 o;
            #pragma unroll
            for (int i = 0; i < 4; ++i) o[i] = (_Float16)(acc[u][v2][i]*inv);
            *(f16x4*)(ob + base + v2*16 + 4*g) = o;
        }
    }
}

// ---------------------------------------------------------------------------
// Kernel 4: out[8192,1024] = ob[8192,2048](fp16) @ fc_w^T(fp16) + fc_b, fp32.
// XCD-swizzled so each XCD works a contiguous mt range (A-panel L2-local).
// ---------------------------------------------------------------------------
__global__ __launch_bounds__(256) void fc_kernel(
    const _Float16* __restrict__ ob,
    const _Float16* __restrict__ wt,
    const float* __restrict__ fcb,
    float* __restrict__ out)
{
    const int lane = threadIdx.x & 63;
    const int w = threadIdx.x >> 6;
    const int orig = blockIdx.x;                     // 2048
    const int blk = ((orig & 7) << 8) | (orig >> 3); // bijective XCD swizzle
    const int wid = blk*4 + w;
    const int mt = wid >> 5;
    const int nt = wid & 31;
    const int r = lane & 15, g = lane >> 4;
    f32x4 acc[2][2];
    #pragma unroll
    for (int u = 0; u < 2; ++u)
      #pragma unroll
      for (int v = 0; v < 2; ++v) acc[u][v] = (f32x4){0.f,0.f,0.f,0.f};
    for (int kt = 0; kt < FCK/32; ++kt) {
        f16x8 afr[2], bfr[2];
        #pragma unroll
        for (int u = 0; u < 2; ++u)
            afr[u] = *(const f16x8*)(ob + (long)(mt*32 + u*16 + r)*FCK + kt*32 + 8*g);
        #pragma unroll
        for (int v = 0; v < 2; ++v)
            bfr[v] = *(const f16x8*)(wt + (long)(nt*32 + v*16 + r)*FCK + kt*32 + 8*g);
        #pragma unroll
        for (int u = 0; u < 2; ++u)
          #pragma unroll
          for (int v = 0; v < 2; ++v)
            acc[u][v] = __builtin_amdgcn_mfma_f32_16x16x32_f16(afr[u], bfr[v], acc[u][v], 0, 0, 0);
    }
    #pragma unroll
    for (int u = 0; u < 2; ++u)
      #pragma unroll
      for (int v = 0; v < 2; ++v) {
        int col = nt*32 + v*16 + r;
        float bias = fcb[col];
        #pragma unroll
        for (int i = 0; i < 4; ++i) {
            int row = mt*32 + u*16 + 4*g + i;
            out[(long)row*EMB + col] = acc[u][v][i] + bias;
        }
      }
}

// ---------------------------------------------------------------------------
extern "C" void kernel_launch(void* const* d_in, const int* in_sizes, int n_in,
                              void* d_out, int out_size, void* d_ws, size_t ws_size,
                              hipStream_t stream) {
    const float* vals = (const float*)d_in[0];
    const float* keys = (const float*)d_in[1];
    const float* qry  = (const float*)d_in[2];
    const float* fmw  = (const float*)d_in[3];
    const float* fmb  = (const float*)d_in[4];
    const float* fcw  = (const float*)d_in[5];
    const float* fcb  = (const float*)d_in[6];
    char* ws = (char*)d_ws;
    const long SZ = 33554432L;                       // 32 MB per fp16 tensor
    _Float16* qf = (_Float16*)(ws);
    _Float16* kf = (_Float16*)(ws + SZ);
    _Float16* vf = (_Float16*)(ws + 2*SZ);
    _Float16* vt = (_Float16*)(ws + 3*SZ);
    _Float16* ob = (_Float16*)(ws + 4*SZ);
    _Float16* wt = (_Float16*)(ws + 5*SZ);           // +4 MB
    float* out = (float*)d_out;

    fmap_kernel<<<dim3(2048), dim3(256), 0, stream>>>(vals, keys, qry, fmw, fmb, qf, kf, vf);
    vtrans_kernel<<<dim3(4096), dim3(256), 0, stream>>>(vf, vt);
    cvt_kernel<<<dim3(1024), dim3(256), 0, stream>>>(fcw, wt);
    attn_kernel<<<dim3(512), dim3(512), 0, stream>>>(qf, kf, vt, ob);
    fc_kernel<<<dim3(2048), dim3(256), 0, stream>>>(ob, wt, fcb, out);
}

// Round 6
// 497.173 us; speedup vs baseline: 1.6260x; 1.6260x over previous
//
#include <hip/hip_runtime.h>
#include <hip/hip_bf16.h>
#include <stdint.h>

#define N_B 4
#define SEQ 2048
#define NH 16
#define ED 128      // expanded feature dim per head
#define EMB 1024
#define FCK 2048    // NH*ED

typedef float f32x4 __attribute__((ext_vector_type(4)));
typedef _Float16 f16x8 __attribute__((ext_vector_type(8)));
typedef _Float16 f16x4 __attribute__((ext_vector_type(4)));

__device__ __forceinline__ void gload16(const void* g, void* l) {
    __builtin_amdgcn_global_load_lds(
        (const __attribute__((address_space(1))) uint32_t*)(g),
        (__attribute__((address_space(3))) uint32_t*)(l), 16, 0, 0);
}

// ---------------------------------------------------------------------------
// Kernel 1: feature map. One wave per (n,s); 16 heads = 16 MFMA rows.
// z via hi/lo fp16 split of x and fm_w (3-term) -> ~fp32-accurate z.
// Outputs (all [nh][s][128] fp16): qf (scaled 1/32), kf, vf.
// ---------------------------------------------------------------------------
__global__ __launch_bounds__(256) void fmap_kernel(
    const float* __restrict__ vals, const float* __restrict__ keys,
    const float* __restrict__ qry,  const float* __restrict__ fmw,
    const float* __restrict__ fmb,
    _Float16* __restrict__ qf, _Float16* __restrict__ kf,
    _Float16* __restrict__ vf)
{
    const int lane = threadIdx.x & 63;
    const int w = threadIdx.x >> 6;
    const int t = blockIdx.x * 4 + w;      // (n*SEQ + s)
    const int n = t >> 11;
    const int s = t & 2047;
    const int r = lane & 15;
    const int g = lane >> 4;

    f16x8 whf[4][2], wlf[4][2];
    #pragma unroll
    for (int te = 0; te < 4; ++te) {
      #pragma unroll
      for (int j = 0; j < 2; ++j) {
        const float* p = fmw + (te*16 + r)*64 + j*32 + 8*g;
        #pragma unroll
        for (int i = 0; i < 8; ++i) {
            float wv = p[i];
            _Float16 hi = (_Float16)wv;
            whf[te][j][i] = hi;
            wlf[te][j][i] = (_Float16)(wv - (float)hi);
        }
      }
    }
    float bias[4];
    #pragma unroll
    for (int te = 0; te < 4; ++te) bias[te] = fmb[te*16 + r];

    const long rowoff = ((long)t*16 + r) * 64;
    const float* srcs[3] = {qry, keys, vals};
    #pragma unroll
    for (int tens = 0; tens < 3; ++tens) {
        const float* src = srcs[tens] + rowoff;
        f16x8 ah[2], al[2];
        #pragma unroll
        for (int j = 0; j < 2; ++j) {
            #pragma unroll
            for (int i = 0; i < 8; ++i) {
                float x = src[j*32 + 8*g + i];
                _Float16 hi = (_Float16)x;
                ah[j][i] = hi;
                al[j][i] = (_Float16)(x - (float)hi);
            }
        }
        #pragma unroll
        for (int te = 0; te < 4; ++te) {
            f32x4 c = (f32x4){0.f,0.f,0.f,0.f};
            c = __builtin_amdgcn_mfma_f32_16x16x32_f16(ah[0], whf[te][0], c, 0, 0, 0);
            c = __builtin_amdgcn_mfma_f32_16x16x32_f16(ah[1], whf[te][1], c, 0, 0, 0);
            c = __builtin_amdgcn_mfma_f32_16x16x32_f16(ah[0], wlf[te][0], c, 0, 0, 0);
            c = __builtin_amdgcn_mfma_f32_16x16x32_f16(ah[1], wlf[te][1], c, 0, 0, 0);
            c = __builtin_amdgcn_mfma_f32_16x16x32_f16(al[0], whf[te][0], c, 0, 0, 0);
            c = __builtin_amdgcn_mfma_f32_16x16x32_f16(al[1], whf[te][1], c, 0, 0, 0);
            #pragma unroll
            for (int i = 0; i < 4; ++i) {
                float z = c[i] + bias[te];
                float ep = __expf(z), en = __expf(-z);
                int hh = 4*g + i;
                int e = te*16 + r;
                long base = (((long)n*NH + hh)*SEQ + s)*ED;
                if (tens == 0) {
                    qf[base + e]      = (_Float16)(ep * 0.03125f);  // fold 1/sqrt(1024)
                    qf[base + 64 + e] = (_Float16)(en * 0.03125f);
                } else if (tens == 1) {
                    kf[base + e]      = (_Float16)ep;
                    kf[base + 64 + e] = (_Float16)en;
                } else {
                    vf[base + e]      = (_Float16)ep;
                    vf[base + 64 + e] = (_Float16)en;
                }
            }
        }
    }
}

// ---------------------------------------------------------------------------
// Kernel 1b: vt[nh][e][s] = vf[nh][s][e] via 64x64 LDS tiles.
// ---------------------------------------------------------------------------
__global__ __launch_bounds__(256) void vtrans_kernel(
    const _Float16* __restrict__ vf, _Float16* __restrict__ vt)
{
    __shared__ _Float16 tile[64][72];
    const int b = blockIdx.x;          // nh*64 + st*2 + et
    const int et = b & 1;
    const int st = (b >> 1) & 31;
    const int nh = b >> 6;
    const _Float16* src = vf + ((long)nh*SEQ + st*64)*ED + et*64;
    const int col4 = (threadIdx.x & 15) * 4;
    const int row0 = threadIdx.x >> 4;
    #pragma unroll
    for (int j = 0; j < 4; ++j) {
        int row = row0 + j*16;
        *(f16x4*)&tile[row][col4] = *(const f16x4*)(src + (long)row*ED + col4);
    }
    __syncthreads();
    _Float16* dst = vt + ((long)nh*ED + et*64)*SEQ + st*64;
    const int erow = threadIdx.x >> 2;
    const int sc0 = (threadIdx.x & 3) * 16;
    f16x8 o0, o1;
    #pragma unroll
    for (int i = 0; i < 8; ++i) o0[i] = tile[sc0 + i][erow];
    #pragma unroll
    for (int i = 0; i < 8; ++i) o1[i] = tile[sc0 + 8 + i][erow];
    *(f16x8*)(dst + (long)erow*SEQ + sc0) = o0;
    *(f16x8*)(dst + (long)erow*SEQ + sc0 + 8) = o1;
}

// ---------------------------------------------------------------------------
// Kernel 2: fc_w fp32 -> fp16
// ---------------------------------------------------------------------------
__global__ __launch_bounds__(256) void cvt_kernel(
    const float* __restrict__ src, _Float16* __restrict__ dst)
{
    long i = ((long)blockIdx.x*256 + threadIdx.x)*8;
    f16x8 o;
    #pragma unroll
    for (int j = 0; j < 8; ++j) o[j] = (_Float16)src[i + j];
    *(f16x8*)(dst + i) = o;
}

// ---------------------------------------------------------------------------
// Kernel 3: flash attention. 512-thread blocks (8 waves) share one KVBLK=64
// LDS-staged K/V stream (double-buffered, global_load_lds, XOR chunk
// swizzle). Wave w owns 32 q-rows; block owns 256 q-rows of one (n,h).
// XCD-swizzled; defer-rescale (THR=8); setprio around MFMA.
// launch_bounds(512,2): 256-VGPR cap -> NO SPILL (R5's (512,4) forced a
// 64-reg cap and spilled acc to scratch: WRITE_SIZE 867 MB).
// ---------------------------------------------------------------------------
__global__ __launch_bounds__(512, 2) void attn_kernel(
    const _Float16* __restrict__ qf,
    const _Float16* __restrict__ kf,
    const _Float16* __restrict__ vt,
    _Float16* __restrict__ ob)
{
    __shared__ char smem[65536];
    const int lane = threadIdx.x & 63;
    const int w = threadIdx.x >> 6;              // 0..7
    const int orig = blockIdx.x;                 // 512 blocks
    const int b = ((orig & 7) << 6) | (orig >> 3);  // bijective XCD swizzle
    const int nh = b >> 3;
    const int n = nh >> 4, h = nh & 15;
    const int qt = (b & 7)*8 + w;                // 0..63, 32 q-rows each
    const int r = lane & 15, g = lane >> 4;

    const _Float16* qb = qf + (long)nh*SEQ*ED;
    const char* kg = (const char*)(kf + (long)nh*SEQ*ED);   // row = 256 B
    const char* vg = (const char*)(vt + (long)nh*ED*SEQ);   // row = SEQ*2 B

    f16x8 qfr[2][4];
    #pragma unroll
    for (int u = 0; u < 2; ++u) {
      #pragma unroll
      for (int j = 0; j < 4; ++j)
        qfr[u][j] = *(const f16x8*)(qb + (long)(qt*32 + u*16 + r)*ED + j*32 + 8*g);
    }

    // cooperative stage of one 64-row K/V tile; 4 gloads per wave
    auto stage = [&](int kt, int bsel) {
        char* Kl = smem + bsel*32768;
        char* Vl = Kl + 16384;
        const char* kts = kg + (long)kt*64*256;
        const char* vts = vg + (long)kt*64*2;
        #pragma unroll
        for (int i = 0; i < 2; ++i) {                 // K rows [w*8, w*8+8)
            int row = w*8 + i*4 + (lane>>4);
            int c = (lane&15) ^ (row&15);
            gload16(kts + (long)row*256 + c*16, Kl + (w*8 + i*4)*256);
        }
        #pragma unroll
        for (int i = 0; i < 2; ++i) {                 // V rows [w*16, w*16+16)
            int row = w*16 + i*8 + (lane>>3);
            int c = (lane&7) ^ (row&7);
            gload16(vts + (long)row*(SEQ*2) + c*16, Vl + (w*16 + i*8)*128);
        }
    };

    f32x4 acc[2][8];
    #pragma unroll
    for (int u = 0; u < 2; ++u)
      #pragma unroll
      for (int v2 = 0; v2 < 8; ++v2) acc[u][v2] = (f32x4){0.f,0.f,0.f,0.f};
    float mrun[2] = {-1e30f, -1e30f};
    float lrun[2] = {0.f, 0.f};

    stage(0, 0);
    __syncthreads();

    for (int kt = 0; kt < SEQ/64; ++kt) {
        const int cur = kt & 1;
        if (kt + 1 < SEQ/64) stage(kt + 1, cur ^ 1);
        const _Float16* Kl = (const _Float16*)(smem + cur*32768);
        const _Float16* Vl = Kl + 8192;

        // QK^T for 64 columns
        f32x4 sc4[2][4];
        #pragma unroll
        for (int c4 = 0; c4 < 4; ++c4) {
            f16x8 khf[4];
            #pragma unroll
            for (int j = 0; j < 4; ++j)
                khf[j] = *(const f16x8*)(Kl + (c4*16 + r)*128 + (((j*4 + g) ^ r) << 3));
            __builtin_amdgcn_s_setprio(1);
            #pragma unroll
            for (int u = 0; u < 2; ++u) {
                f32x4 s = (f32x4){0.f,0.f,0.f,0.f};
                #pragma unroll
                for (int j = 0; j < 4; ++j)
                    s = __builtin_amdgcn_mfma_f32_16x16x32_f16(khf[j], qfr[u][j], s, 0, 0, 0);
                sc4[u][c4] = s;
            }
            __builtin_amdgcn_s_setprio(0);
        }

        // online softmax with defer-rescale
        f16x4 pbv[2][4];
        #pragma unroll
        for (int u = 0; u < 2; ++u) {
            float mx = sc4[u][0][0];
            #pragma unroll
            for (int c4 = 0; c4 < 4; ++c4)
                #pragma unroll
                for (int i2 = 0; i2 < 4; ++i2) mx = fmaxf(mx, sc4[u][c4][i2]);
            mx = fmaxf(mx, __shfl_xor(mx, 16, 64));
            mx = fmaxf(mx, __shfl_xor(mx, 32, 64));   // uniform per q-row
            if (__any(mx > mrun[u] + 8.0f)) {
                float mnew = fmaxf(mrun[u], mx);
                float corr = __expf(mrun[u] - mnew);
                lrun[u] *= corr;
                #pragma unroll
                for (int v2 = 0; v2 < 8; ++v2) {
                    acc[u][v2][0] *= corr; acc[u][v2][1] *= corr;
                    acc[u][v2][2] *= corr; acc[u][v2][3] *= corr;
                }
                mrun[u] = mnew;
            }
            float rs = 0.f;
            #pragma unroll
            for (int c4 = 0; c4 < 4; ++c4) {
                f16x4 p;
                #pragma unroll
                for (int i2 = 0; i2 < 4; ++i2) {
                    float pv = __expf(sc4[u][c4][i2] - mrun[u]);   // <= e^8
                    p[i2] = (_Float16)pv;
                    rs += (float)p[i2];            // denom from rounded p
                }
                pbv[u][c4] = p;
            }
            rs += __shfl_xor(rs, 16, 64);
            rs += __shfl_xor(rs, 32, 64);
            lrun[u] += rs;
        }

        // PV: 64-col tile in 4 sub-chunks of 16
        #pragma unroll
        for (int kq = 0; kq < 4; ++kq) {
            f16x4 vfr[8];
            #pragma unroll
            for (int v2 = 0; v2 < 8; ++v2)
                vfr[v2] = *(const f16x4*)(Vl + (v2*16 + r)*64 +
                            ((((kq*2 + (g>>1)) ^ (r&7)) << 3) + ((g&1) << 2)));
            __builtin_amdgcn_s_setprio(1);
            #pragma unroll
            for (int u = 0; u < 2; ++u)
                #pragma unroll
                for (int v2 = 0; v2 < 8; ++v2)
                    acc[u][v2] = __builtin_amdgcn_mfma_f32_16x16x16f16(vfr[v2], pbv[u][kq], acc[u][v2], 0, 0, 0);
            __builtin_amdgcn_s_setprio(0);
        }
        __syncthreads();   // drains vmcnt (stage kt+1 done) + protects buffers
    }

    #pragma unroll
    for (int u = 0; u < 2; ++u) {
        float inv = 1.0f / lrun[u];
        int q = qt*32 + u*16 + r;
        long base = ((long)n*SEQ + q)*FCK + h*ED;
        #pragma unroll
        for (int v2 = 0; v2 < 8; ++v2) {
            f16x4 o;
            #pragma unroll
            for (int i = 0; i < 4; ++i) o[i] = (_Float16)(acc[u][v2][i]*inv);
            *(f16x4*)(ob + base + v2*16 + 4*g) = o;
        }
    }
}

// ---------------------------------------------------------------------------
// Kernel 4: out[8192,1024] = ob[8192,2048](fp16) @ fc_w^T(fp16) + fc_b, fp32.
// ---------------------------------------------------------------------------
__global__ __launch_bounds__(256) void fc_kernel(
    const _Float16* __restrict__ ob,
    const _Float16* __restrict__ wt,
    const float* __restrict__ fcb,
    float* __restrict__ out)
{
    const int lane = threadIdx.x & 63;
    const int w = threadIdx.x >> 6;
    const int orig = blockIdx.x;                     // 2048
    const int blk = ((orig & 7) << 8) | (orig >> 3); // bijective XCD swizzle
    const int wid = blk*4 + w;
    const int mt = wid >> 5;
    const int nt = wid & 31;
    const int r = lane & 15, g = lane >> 4;
    f32x4 acc[2][2];
    #pragma unroll
    for (int u = 0; u < 2; ++u)
      #pragma unroll
      for (int v = 0; v < 2; ++v) acc[u][v] = (f32x4){0.f,0.f,0.f,0.f};
    for (int kt = 0; kt < FCK/32; ++kt) {
        f16x8 afr[2], bfr[2];
        #pragma unroll
        for (int u = 0; u < 2; ++u)
            afr[u] = *(const f16x8*)(ob + (long)(mt*32 + u*16 + r)*FCK + kt*32 + 8*g);
        #pragma unroll
        for (int v = 0; v < 2; ++v)
            bfr[v] = *(const f16x8*)(wt + (long)(nt*32 + v*16 + r)*FCK + kt*32 + 8*g);
        #pragma unroll
        for (int u = 0; u < 2; ++u)
          #pragma unroll
          for (int v = 0; v < 2; ++v)
            acc[u][v] = __builtin_amdgcn_mfma_f32_16x16x32_f16(afr[u], bfr[v], acc[u][v], 0, 0, 0);
    }
    #pragma unroll
    for (int u = 0; u < 2; ++u)
      #pragma unroll
      for (int v = 0; v < 2; ++v) {
        int col = nt*32 + v*16 + r;
        float bias = fcb[col];
        #pragma unroll
        for (int i = 0; i < 4; ++i) {
            int row = mt*32 + u*16 + 4*g + i;
            out[(long)row*EMB + col] = acc[u][v][i] + bias;
        }
      }
}

// ---------------------------------------------------------------------------
extern "C" void kernel_launch(void* const* d_in, const int* in_sizes, int n_in,
                              void* d_out, int out_size, void* d_ws, size_t ws_size,
                              hipStream_t stream) {
    const float* vals = (const float*)d_in[0];
    const float* keys = (const float*)d_in[1];
    const float* qry  = (const float*)d_in[2];
    const float* fmw  = (const float*)d_in[3];
    const float* fmb  = (const float*)d_in[4];
    const float* fcw  = (const float*)d_in[5];
    const float* fcb  = (const float*)d_in[6];
    char* ws = (char*)d_ws;
    const long SZ = 33554432L;                       // 32 MB per fp16 tensor
    _Float16* qf = (_Float16*)(ws);
    _Float16* kf = (_Float16*)(ws + SZ);
    _Float16* vf = (_Float16*)(ws + 2*SZ);
    _Float16* vt = (_Float16*)(ws + 3*SZ);
    _Float16* ob = (_Float16*)(ws + 4*SZ);
    _Float16* wt = (_Float16*)(ws + 5*SZ);           // +4 MB
    float* out = (float*)d_out;

    fmap_kernel<<<dim3(2048), dim3(256), 0, stream>>>(vals, keys, qry, fmw, fmb, qf, kf, vf);
    vtrans_kernel<<<dim3(4096), dim3(256), 0, stream>>>(vf, vt);
    cvt_kernel<<<dim3(1024), dim3(256), 0, stream>>>(fcw, wt);
    attn_kernel<<<dim3(512), dim3(512), 0, stream>>>(qf, kf, vt, ob);
    fc_kernel<<<dim3(2048), dim3(256), 0, stream>>>(ob, wt, fcb, out);
}

// Round 7
// 308.810 us; speedup vs baseline: 2.6179x; 1.6100x over previous
//
#include <hip/hip_runtime.h>
#include <hip/hip_bf16.h>
#include <stdint.h>

#define N_B 4
#define SEQ 2048
#define NH 16
#define ED 128      // expanded feature dim per head
#define EMB 1024
#define FCK 2048    // NH*ED

typedef float f32x4 __attribute__((ext_vector_type(4)));
typedef _Float16 f16x8 __attribute__((ext_vector_type(8)));
typedef _Float16 f16x4 __attribute__((ext_vector_type(4)));

__device__ __forceinline__ void gload16(const void* g, void* l) {
    __builtin_amdgcn_global_load_lds(
        (const __attribute__((address_space(1))) uint32_t*)(g),
        (__attribute__((address_space(3))) uint32_t*)(l), 16, 0, 0);
}

// ---------------------------------------------------------------------------
// Kernel 1: feature map. One wave per (n,s); 16 heads = 16 MFMA rows.
// z via hi/lo fp16 split of x and fm_w (3-term) -> ~fp32-accurate z.
// Outputs (all [nh][s][128] fp16): qf (scaled 1/32), kf, vf.
// ---------------------------------------------------------------------------
__global__ __launch_bounds__(256) void fmap_kernel(
    const float* __restrict__ vals, const float* __restrict__ keys,
    const float* __restrict__ qry,  const float* __restrict__ fmw,
    const float* __restrict__ fmb,
    _Float16* __restrict__ qf, _Float16* __restrict__ kf,
    _Float16* __restrict__ vf)
{
    const int lane = threadIdx.x & 63;
    const int w = threadIdx.x >> 6;
    const int t = blockIdx.x * 4 + w;      // (n*SEQ + s)
    const int n = t >> 11;
    const int s = t & 2047;
    const int r = lane & 15;
    const int g = lane >> 4;

    f16x8 whf[4][2], wlf[4][2];
    #pragma unroll
    for (int te = 0; te < 4; ++te) {
      #pragma unroll
      for (int j = 0; j < 2; ++j) {
        const float* p = fmw + (te*16 + r)*64 + j*32 + 8*g;
        #pragma unroll
        for (int i = 0; i < 8; ++i) {
            float wv = p[i];
            _Float16 hi = (_Float16)wv;
            whf[te][j][i] = hi;
            wlf[te][j][i] = (_Float16)(wv - (float)hi);
        }
      }
    }
    float bias[4];
    #pragma unroll
    for (int te = 0; te < 4; ++te) bias[te] = fmb[te*16 + r];

    const long rowoff = ((long)t*16 + r) * 64;
    const float* srcs[3] = {qry, keys, vals};
    #pragma unroll
    for (int tens = 0; tens < 3; ++tens) {
        const float* src = srcs[tens] + rowoff;
        f16x8 ah[2], al[2];
        #pragma unroll
        for (int j = 0; j < 2; ++j) {
            #pragma unroll
            for (int i = 0; i < 8; ++i) {
                float x = src[j*32 + 8*g + i];
                _Float16 hi = (_Float16)x;
                ah[j][i] = hi;
                al[j][i] = (_Float16)(x - (float)hi);
            }
        }
        #pragma unroll
        for (int te = 0; te < 4; ++te) {
            f32x4 c = (f32x4){0.f,0.f,0.f,0.f};
            c = __builtin_amdgcn_mfma_f32_16x16x32_f16(ah[0], whf[te][0], c, 0, 0, 0);
            c = __builtin_amdgcn_mfma_f32_16x16x32_f16(ah[1], whf[te][1], c, 0, 0, 0);
            c = __builtin_amdgcn_mfma_f32_16x16x32_f16(ah[0], wlf[te][0], c, 0, 0, 0);
            c = __builtin_amdgcn_mfma_f32_16x16x32_f16(ah[1], wlf[te][1], c, 0, 0, 0);
            c = __builtin_amdgcn_mfma_f32_16x16x32_f16(al[0], whf[te][0], c, 0, 0, 0);
            c = __builtin_amdgcn_mfma_f32_16x16x32_f16(al[1], whf[te][1], c, 0, 0, 0);
            #pragma unroll
            for (int i = 0; i < 4; ++i) {
                float z = c[i] + bias[te];
                float ep = __expf(z), en = __expf(-z);
                int hh = 4*g + i;
                int e = te*16 + r;
                long base = (((long)n*NH + hh)*SEQ + s)*ED;
                if (tens == 0) {
                    qf[base + e]      = (_Float16)(ep * 0.03125f);  // fold 1/sqrt(1024)
                    qf[base + 64 + e] = (_Float16)(en * 0.03125f);
                } else if (tens == 1) {
                    kf[base + e]      = (_Float16)ep;
                    kf[base + 64 + e] = (_Float16)en;
                } else {
                    vf[base + e]      = (_Float16)ep;
                    vf[base + 64 + e] = (_Float16)en;
                }
            }
        }
    }
}

// ---------------------------------------------------------------------------
// Kernel 1b: vt[nh][e][s] = vf[nh][s][e] via 64x64 LDS tiles.
// ---------------------------------------------------------------------------
__global__ __launch_bounds__(256) void vtrans_kernel(
    const _Float16* __restrict__ vf, _Float16* __restrict__ vt)
{
    __shared__ _Float16 tile[64][72];
    const int b = blockIdx.x;          // nh*64 + st*2 + et
    const int et = b & 1;
    const int st = (b >> 1) & 31;
    const int nh = b >> 6;
    const _Float16* src = vf + ((long)nh*SEQ + st*64)*ED + et*64;
    const int col4 = (threadIdx.x & 15) * 4;
    const int row0 = threadIdx.x >> 4;
    #pragma unroll
    for (int j = 0; j < 4; ++j) {
        int row = row0 + j*16;
        *(f16x4*)&tile[row][col4] = *(const f16x4*)(src + (long)row*ED + col4);
    }
    __syncthreads();
    _Float16* dst = vt + ((long)nh*ED + et*64)*SEQ + st*64;
    const int erow = threadIdx.x >> 2;
    const int sc0 = (threadIdx.x & 3) * 16;
    f16x8 o0, o1;
    #pragma unroll
    for (int i = 0; i < 8; ++i) o0[i] = tile[sc0 + i][erow];
    #pragma unroll
    for (int i = 0; i < 8; ++i) o1[i] = tile[sc0 + 8 + i][erow];
    *(f16x8*)(dst + (long)erow*SEQ + sc0) = o0;
    *(f16x8*)(dst + (long)erow*SEQ + sc0 + 8) = o1;
}

// ---------------------------------------------------------------------------
// Kernel 2: fc_w fp32 -> fp16
// ---------------------------------------------------------------------------
__global__ __launch_bounds__(256) void cvt_kernel(
    const float* __restrict__ src, _Float16* __restrict__ dst)
{
    long i = ((long)blockIdx.x*256 + threadIdx.x)*8;
    f16x8 o;
    #pragma unroll
    for (int j = 0; j < 8; ++j) o[j] = (_Float16)src[i + j];
    *(f16x8*)(dst + i) = o;
}

// ---------------------------------------------------------------------------
// Kernel 3: flash attention. 512-thread blocks (8 waves) share one KVBLK=64
// LDS-staged K/V stream (double-buffered, global_load_lds, XOR chunk
// swizzle). Wave w owns 32 q-rows; block owns 256 q-rows of one (n,h).
// XCD-swizzled; defer-rescale (THR=8); setprio around MFMA.
// launch_bounds(512,2): 256-VGPR cap -> no spill.
// ---------------------------------------------------------------------------
__global__ __launch_bounds__(512, 2) void attn_kernel(
    const _Float16* __restrict__ qf,
    const _Float16* __restrict__ kf,
    const _Float16* __restrict__ vt,
    _Float16* __restrict__ ob)
{
    __shared__ char smem[65536];
    const int lane = threadIdx.x & 63;
    const int w = threadIdx.x >> 6;              // 0..7
    const int orig = blockIdx.x;                 // 512 blocks
    const int b = ((orig & 7) << 6) | (orig >> 3);  // bijective XCD swizzle
    const int nh = b >> 3;
    const int n = nh >> 4, h = nh & 15;
    const int qt = (b & 7)*8 + w;                // 0..63, 32 q-rows each
    const int r = lane & 15, g = lane >> 4;

    const _Float16* qb = qf + (long)nh*SEQ*ED;
    const char* kg = (const char*)(kf + (long)nh*SEQ*ED);   // row = 256 B
    const char* vg = (const char*)(vt + (long)nh*ED*SEQ);   // row = SEQ*2 B

    f16x8 qfr[2][4];
    #pragma unroll
    for (int u = 0; u < 2; ++u) {
      #pragma unroll
      for (int j = 0; j < 4; ++j)
        qfr[u][j] = *(const f16x8*)(qb + (long)(qt*32 + u*16 + r)*ED + j*32 + 8*g);
    }

    // cooperative stage of one 64-row K/V tile; 4 gloads per wave
    auto stage = [&](int kt, int bsel) {
        char* Kl = smem + bsel*32768;
        char* Vl = Kl + 16384;
        const char* kts = kg + (long)kt*64*256;
        const char* vts = vg + (long)kt*64*2;
        #pragma unroll
        for (int i = 0; i < 2; ++i) {                 // K rows [w*8, w*8+8)
            int row = w*8 + i*4 + (lane>>4);
            int c = (lane&15) ^ (row&15);
            gload16(kts + (long)row*256 + c*16, Kl + (w*8 + i*4)*256);
        }
        #pragma unroll
        for (int i = 0; i < 2; ++i) {                 // V rows [w*16, w*16+16)
            int row = w*16 + i*8 + (lane>>3);
            int c = (lane&7) ^ (row&7);
            gload16(vts + (long)row*(SEQ*2) + c*16, Vl + (w*16 + i*8)*128);
        }
    };

    f32x4 acc[2][8];
    #pragma unroll
    for (int u = 0; u < 2; ++u)
      #pragma unroll
      for (int v2 = 0; v2 < 8; ++v2) acc[u][v2] = (f32x4){0.f,0.f,0.f,0.f};
    float mrun[2] = {-1e30f, -1e30f};
    float lrun[2] = {0.f, 0.f};

    stage(0, 0);
    __syncthreads();

    for (int kt = 0; kt < SEQ/64; ++kt) {
        const int cur = kt & 1;
        if (kt + 1 < SEQ/64) stage(kt + 1, cur ^ 1);
        const _Float16* Kl = (const _Float16*)(smem + cur*32768);
        const _Float16* Vl = Kl + 8192;

        // QK^T for 64 columns
        f32x4 sc4[2][4];
        #pragma unroll
        for (int c4 = 0; c4 < 4; ++c4) {
            f16x8 khf[4];
            #pragma unroll
            for (int j = 0; j < 4; ++j)
                khf[j] = *(const f16x8*)(Kl + (c4*16 + r)*128 + (((j*4 + g) ^ r) << 3));
            __builtin_amdgcn_s_setprio(1);
            #pragma unroll
            for (int u = 0; u < 2; ++u) {
                f32x4 s = (f32x4){0.f,0.f,0.f,0.f};
                #pragma unroll
                for (int j = 0; j < 4; ++j)
                    s = __builtin_amdgcn_mfma_f32_16x16x32_f16(khf[j], qfr[u][j], s, 0, 0, 0);
                sc4[u][c4] = s;
            }
            __builtin_amdgcn_s_setprio(0);
        }

        // online softmax with defer-rescale
        f16x4 pbv[2][4];
        #pragma unroll
        for (int u = 0; u < 2; ++u) {
            float mx = sc4[u][0][0];
            #pragma unroll
            for (int c4 = 0; c4 < 4; ++c4)
                #pragma unroll
                for (int i2 = 0; i2 < 4; ++i2) mx = fmaxf(mx, sc4[u][c4][i2]);
            mx = fmaxf(mx, __shfl_xor(mx, 16, 64));
            mx = fmaxf(mx, __shfl_xor(mx, 32, 64));   // uniform per q-row
            if (__any(mx > mrun[u] + 8.0f)) {
                float mnew = fmaxf(mrun[u], mx);
                float corr = __expf(mrun[u] - mnew);
                lrun[u] *= corr;
                #pragma unroll
                for (int v2 = 0; v2 < 8; ++v2) {
                    acc[u][v2][0] *= corr; acc[u][v2][1] *= corr;
                    acc[u][v2][2] *= corr; acc[u][v2][3] *= corr;
                }
                mrun[u] = mnew;
            }
            float rs = 0.f;
            #pragma unroll
            for (int c4 = 0; c4 < 4; ++c4) {
                f16x4 p;
                #pragma unroll
                for (int i2 = 0; i2 < 4; ++i2) {
                    float pv = __expf(sc4[u][c4][i2] - mrun[u]);   // <= e^8
                    p[i2] = (_Float16)pv;
                    rs += (float)p[i2];            // denom from rounded p
                }
                pbv[u][c4] = p;
            }
            rs += __shfl_xor(rs, 16, 64);
            rs += __shfl_xor(rs, 32, 64);
            lrun[u] += rs;
        }

        // PV: 64-col tile in 4 sub-chunks of 16
        #pragma unroll
        for (int kq = 0; kq < 4; ++kq) {
            f16x4 vfr[8];
            #pragma unroll
            for (int v2 = 0; v2 < 8; ++v2)
                vfr[v2] = *(const f16x4*)(Vl + (v2*16 + r)*64 +
                            ((((kq*2 + (g>>1)) ^ (r&7)) << 3) + ((g&1) << 2)));
            __builtin_amdgcn_s_setprio(1);
            #pragma unroll
            for (int u = 0; u < 2; ++u)
                #pragma unroll
                for (int v2 = 0; v2 < 8; ++v2)
                    acc[u][v2] = __builtin_amdgcn_mfma_f32_16x16x16f16(vfr[v2], pbv[u][kq], acc[u][v2], 0, 0, 0);
            __builtin_amdgcn_s_setprio(0);
        }
        __syncthreads();   // drains vmcnt (stage kt+1 done) + protects buffers
    }

    #pragma unroll
    for (int u = 0; u < 2; ++u) {
        float inv = 1.0f / lrun[u];
        int q = qt*32 + u*16 + r;
        long base = ((long)n*SEQ + q)*FCK + h*ED;
        #pragma unroll
        for (int v2 = 0; v2 < 8; ++v2) {
            f16x4 o;
            #pragma unroll
            for (int i = 0; i < 4; ++i) o[i] = (_Float16)(acc[u][v2][i]*inv);
            *(f16x4*)(ob + base + v2*16 + 4*g) = o;
        }
    }
}

// ---------------------------------------------------------------------------
// Kernel 4: out[8192,1024] = ob[8192,2048](fp16) @ fc_w^T(fp16) + fc_b, fp32.
// m97-style 128x128 tile, BK=32, double-buffered LDS via global_load_lds,
// XOR chunk swizzle (chunk ^= (row>>1)&3 -> 2-way on ds_read_b128 = free).
// 4 waves (2x2), 64x64 per wave. XCD grouping: 8 mt-rows per XCD so each
// A-panel is fetched ~once per chip.
// ---------------------------------------------------------------------------
__global__ __launch_bounds__(256) void fc_kernel(
    const _Float16* __restrict__ ob,
    const _Float16* __restrict__ wt,
    const float* __restrict__ fcb,
    float* __restrict__ out)
{
    __shared__ char smem[32768];            // 2 x (A 8KB + B 8KB)
    const int lane = threadIdx.x & 63;
    const int w = threadIdx.x >> 6;         // 0..3
    const int wm = w >> 1, wn = w & 1;      // 2x2 wave grid
    const int r = lane & 15, g = lane >> 4;

    const int orig = blockIdx.x;            // 512 blocks
    const int tile = ((orig & 7) << 6) | (orig >> 3);  // XCD-contiguous
    const int mt = tile >> 3;               // 0..63
    const int nt = tile & 7;                // 0..7

    const char* Ag = (const char*)(ob + (long)mt*128*FCK);
    const char* Bg = (const char*)(wt + (long)nt*128*FCK);

    // stage one 128x32 A-tile + B-tile into buffer bsel (K-step kt)
    auto stage = [&](int kt, int bsel) {
        char* As = smem + bsel*16384;
        char* Bs = As + 8192;
        #pragma unroll
        for (int rnd = 0; rnd < 2; ++rnd) {
            int row = rnd*64 + w*16 + (lane >> 2);
            int cs = (lane & 3) ^ ((row >> 1) & 3);
            gload16(Ag + (long)row*(FCK*2) + kt*64 + cs*16, As + rnd*4096 + w*1024);
            gload16(Bg + (long)row*(FCK*2) + kt*64 + cs*16, Bs + rnd*4096 + w*1024);
        }
    };

    f32x4 acc[4][4];
    #pragma unroll
    for (int u = 0; u < 4; ++u)
      #pragma unroll
      for (int v = 0; v < 4; ++v) acc[u][v] = (f32x4){0.f,0.f,0.f,0.f};

    stage(0, 0);
    __syncthreads();

    for (int kt = 0; kt < FCK/32; ++kt) {
        const int cur = kt & 1;
        if (kt + 1 < FCK/32) stage(kt + 1, cur ^ 1);
        const char* As = smem + cur*16384;
        const char* Bs = As + 8192;

        f16x8 afr[4], bfr[4];
        #pragma unroll
        for (int u = 0; u < 4; ++u) {
            int row = wm*64 + u*16 + r;
            afr[u] = *(const f16x8*)(As + row*64 + ((g ^ ((row >> 1) & 3)) << 4));
        }
        #pragma unroll
        for (int v = 0; v < 4; ++v) {
            int row = wn*64 + v*16 + r;
            bfr[v] = *(const f16x8*)(Bs + row*64 + ((g ^ ((row >> 1) & 3)) << 4));
        }
        __builtin_amdgcn_s_setprio(1);
        #pragma unroll
        for (int u = 0; u < 4; ++u)
          #pragma unroll
          for (int v = 0; v < 4; ++v)
            acc[u][v] = __builtin_amdgcn_mfma_f32_16x16x32_f16(afr[u], bfr[v], acc[u][v], 0, 0, 0);
        __builtin_amdgcn_s_setprio(0);
        __syncthreads();
    }

    #pragma unroll
    for (int u = 0; u < 4; ++u)
      #pragma unroll
      for (int v = 0; v < 4; ++v) {
        int col = nt*128 + wn*64 + v*16 + r;
        float bias = fcb[col];
        #pragma unroll
        for (int i = 0; i < 4; ++i) {
            int row = mt*128 + wm*64 + u*16 + 4*g + i;
            out[(long)row*EMB + col] = acc[u][v][i] + bias;
        }
      }
}

// ---------------------------------------------------------------------------
extern "C" void kernel_launch(void* const* d_in, const int* in_sizes, int n_in,
                              void* d_out, int out_size, void* d_ws, size_t ws_size,
                              hipStream_t stream) {
    const float* vals = (const float*)d_in[0];
    const float* keys = (const float*)d_in[1];
    const float* qry  = (const float*)d_in[2];
    const float* fmw  = (const float*)d_in[3];
    const float* fmb  = (const float*)d_in[4];
    const float* fcw  = (const float*)d_in[5];
    const float* fcb  = (const float*)d_in[6];
    char* ws = (char*)d_ws;
    const long SZ = 33554432L;                       // 32 MB per fp16 tensor
    _Float16* qf = (_Float16*)(ws);
    _Float16* kf = (_Float16*)(ws + SZ);
    _Float16* vf = (_Float16*)(ws + 2*SZ);
    _Float16* vt = (_Float16*)(ws + 3*SZ);
    _Float16* ob = (_Float16*)(ws + 4*SZ);
    _Float16* wt = (_Float16*)(ws + 5*SZ);           // +4 MB
    float* out = (float*)d_out;

    fmap_kernel<<<dim3(2048), dim3(256), 0, stream>>>(vals, keys, qry, fmw, fmb, qf, kf, vf);
    vtrans_kernel<<<dim3(4096), dim3(256), 0, stream>>>(vf, vt);
    cvt_kernel<<<dim3(1024), dim3(256), 0, stream>>>(fcw, wt);
    attn_kernel<<<dim3(512), dim3(512), 0, stream>>>(qf, kf, vt, ob);
    fc_kernel<<<dim3(512), dim3(256), 0, stream>>>(ob, wt, fcb, out);
}

// Round 9
// 297.306 us; speedup vs baseline: 2.7192x; 1.0387x over previous
//
#include <hip/hip_runtime.h>
#include <hip/hip_bf16.h>
#include <stdint.h>

#define N_B 4
#define SEQ 2048
#define NH 16
#define ED 128      // expanded feature dim per head
#define EMB 1024
#define FCK 2048    // NH*ED

typedef float f32x4 __attribute__((ext_vector_type(4)));
typedef float f32x16 __attribute__((ext_vector_type(16)));
typedef _Float16 f16x8 __attribute__((ext_vector_type(8)));
typedef _Float16 f16x4 __attribute__((ext_vector_type(4)));
typedef __fp16 fp16v2 __attribute__((ext_vector_type(2)));

__device__ __forceinline__ void gload16(const void* g, void* l) {
    __builtin_amdgcn_global_load_lds(
        (const __attribute__((address_space(1))) uint32_t*)(g),
        (__attribute__((address_space(3))) uint32_t*)(l), 16, 0, 0);
}

__device__ __forceinline__ int pk2(float a, float b) {
    union { fp16v2 h; int i; } u;
    u.h = __builtin_amdgcn_cvt_pkrtz(a, b);
    return u.i;
}

__device__ __forceinline__ f16x8 frag4(int d0, int d1, int d2, int d3) {
    union { int i[4]; f16x8 v; } u;
    u.i[0] = d0; u.i[1] = d1; u.i[2] = d2; u.i[3] = d3;
    return u.v;
}

// ---------------------------------------------------------------------------
// Kernel 1: feature map. One wave per (n,s); 16 heads = 16 MFMA rows.
// z via hi/lo fp16 split of x and fm_w (3-term) -> ~fp32-accurate z.
// Outputs (all [nh][s][128] fp16): qf (scaled log2e/32: QK logits come out in
// log2 units so softmax uses raw v_exp_f32), kf, vf.
// ---------------------------------------------------------------------------
__global__ __launch_bounds__(256) void fmap_kernel(
    const float* __restrict__ vals, const float* __restrict__ keys,
    const float* __restrict__ qry,  const float* __restrict__ fmw,
    const float* __restrict__ fmb,
    _Float16* __restrict__ qf, _Float16* __restrict__ kf,
    _Float16* __restrict__ vf)
{
    const int lane = threadIdx.x & 63;
    const int w = threadIdx.x >> 6;
    const int t = blockIdx.x * 4 + w;      // (n*SEQ + s)
    const int n = t >> 11;
    const int s = t & 2047;
    const int r = lane & 15;
    const int g = lane >> 4;

    f16x8 whf[4][2], wlf[4][2];
    #pragma unroll
    for (int te = 0; te < 4; ++te) {
      #pragma unroll
      for (int j = 0; j < 2; ++j) {
        const float* p = fmw + (te*16 + r)*64 + j*32 + 8*g;
        #pragma unroll
        for (int i = 0; i < 8; ++i) {
            float wv = p[i];
            _Float16 hi = (_Float16)wv;
            whf[te][j][i] = hi;
            wlf[te][j][i] = (_Float16)(wv - (float)hi);
        }
      }
    }
    float bias[4];
    #pragma unroll
    for (int te = 0; te < 4; ++te) bias[te] = fmb[te*16 + r];

    const float QSCL = 0.03125f * 1.4426950408889634f;   // (1/sqrt(1024))*log2(e)

    const long rowoff = ((long)t*16 + r) * 64;
    const float* srcs[3] = {qry, keys, vals};
    #pragma unroll
    for (int tens = 0; tens < 3; ++tens) {
        const float* src = srcs[tens] + rowoff;
        f16x8 ah[2], al[2];
        #pragma unroll
        for (int j = 0; j < 2; ++j) {
            #pragma unroll
            for (int i = 0; i < 8; ++i) {
                float x = src[j*32 + 8*g + i];
                _Float16 hi = (_Float16)x;
                ah[j][i] = hi;
                al[j][i] = (_Float16)(x - (float)hi);
            }
        }
        #pragma unroll
        for (int te = 0; te < 4; ++te) {
            f32x4 c = (f32x4){0.f,0.f,0.f,0.f};
            c = __builtin_amdgcn_mfma_f32_16x16x32_f16(ah[0], whf[te][0], c, 0, 0, 0);
            c = __builtin_amdgcn_mfma_f32_16x16x32_f16(ah[1], whf[te][1], c, 0, 0, 0);
            c = __builtin_amdgcn_mfma_f32_16x16x32_f16(ah[0], wlf[te][0], c, 0, 0, 0);
            c = __builtin_amdgcn_mfma_f32_16x16x32_f16(ah[1], wlf[te][1], c, 0, 0, 0);
            c = __builtin_amdgcn_mfma_f32_16x16x32_f16(al[0], whf[te][0], c, 0, 0, 0);
            c = __builtin_amdgcn_mfma_f32_16x16x32_f16(al[1], whf[te][1], c, 0, 0, 0);
            #pragma unroll
            for (int i = 0; i < 4; ++i) {
                float z = c[i] + bias[te];
                float ep = __expf(z), en = __expf(-z);
                int hh = 4*g + i;
                int e = te*16 + r;
                long base = (((long)n*NH + hh)*SEQ + s)*ED;
                if (tens == 0) {
                    qf[base + e]      = (_Float16)(ep * QSCL);
                    qf[base + 64 + e] = (_Float16)(en * QSCL);
                } else if (tens == 1) {
                    kf[base + e]      = (_Float16)ep;
                    kf[base + 64 + e] = (_Float16)en;
                } else {
                    vf[base + e]      = (_Float16)ep;
                    vf[base + 64 + e] = (_Float16)en;
                }
            }
        }
    }
}

// ---------------------------------------------------------------------------
// Kernel 1b: vt[nh][e][s] = vf[nh][s][e] via 64x64 LDS tiles.
// ---------------------------------------------------------------------------
__global__ __launch_bounds__(256) void vtrans_kernel(
    const _Float16* __restrict__ vf, _Float16* __restrict__ vt)
{
    __shared__ _Float16 tile[64][72];
    const int b = blockIdx.x;          // nh*64 + st*2 + et
    const int et = b & 1;
    const int st = (b >> 1) & 31;
    const int nh = b >> 6;
    const _Float16* src = vf + ((long)nh*SEQ + st*64)*ED + et*64;
    const int col4 = (threadIdx.x & 15) * 4;
    const int row0 = threadIdx.x >> 4;
    #pragma unroll
    for (int j = 0; j < 4; ++j) {
        int row = row0 + j*16;
        *(f16x4*)&tile[row][col4] = *(const f16x4*)(src + (long)row*ED + col4);
    }
    __syncthreads();
    _Float16* dst = vt + ((long)nh*ED + et*64)*SEQ + st*64;
    const int erow = threadIdx.x >> 2;
    const int sc0 = (threadIdx.x & 3) * 16;
    f16x8 o0, o1;
    #pragma unroll
    for (int i = 0; i < 8; ++i) o0[i] = tile[sc0 + i][erow];
    #pragma unroll
    for (int i = 0; i < 8; ++i) o1[i] = tile[sc0 + 8 + i][erow];
    *(f16x8*)(dst + (long)erow*SEQ + sc0) = o0;
    *(f16x8*)(dst + (long)erow*SEQ + sc0 + 8) = o1;
}

// ---------------------------------------------------------------------------
// Kernel 2: fc_w fp32 -> fp16
// ---------------------------------------------------------------------------
__global__ __launch_bounds__(256) void cvt_kernel(
    const float* __restrict__ src, _Float16* __restrict__ dst)
{
    long i = ((long)blockIdx.x*256 + threadIdx.x)*8;
    f16x8 o;
    #pragma unroll
    for (int j = 0; j < 8; ++j) o[j] = (_Float16)src[i + j];
    *(f16x8*)(dst + i) = o;
}

// ---------------------------------------------------------------------------
// Kernel 3: flash attention, 32x32 MFMA structure (m214/HK-style).
// 512-thread blocks (8 waves) share one KVBLK=64 LDS-staged K/V stream
// (double-buffered, global_load_lds, XOR chunk swizzle). Wave owns 32 q-rows.
// Swapped QK^T via mfma_32x32x16(A=K, B=Q^T): S^T lane layout col=q=lane&31,
// row k = (reg&3)+8*(reg>>2)+4*(lane>>5)  -> q-col lane-local; softmax max/sum
// finish with one shfl_xor(32). P -> PV B-operand built in-register with
// cvt_pkrtz pairs + v_permlane32_swap (2 swaps per 16-k slice).
// PV via mfma_32x32x16(A=V^T, B=P). 32 MFMA/kt (was 96).
// Everything in log2 domain (exp2f); defer-rescale THR=11 (log2 units).
// ---------------------------------------------------------------------------
__global__ __launch_bounds__(512, 2) void attn_kernel(
    const _Float16* __restrict__ qf,
    const _Float16* __restrict__ kf,
    const _Float16* __restrict__ vt,
    _Float16* __restrict__ ob)
{
    __shared__ char smem[65536];
    const int lane = threadIdx.x & 63;
    const int w = threadIdx.x >> 6;              // 0..7
    const int orig = blockIdx.x;                 // 512 blocks
    const int b = ((orig & 7) << 6) | (orig >> 3);  // bijective XCD swizzle
    const int nh = b >> 3;
    const int n = nh >> 4, h = nh & 15;
    const int qt = (b & 7)*8 + w;                // 0..63, 32 q-rows each
    const int q32 = lane & 31;                   // q-col / A-row index
    const int hl = lane >> 5;                    // lane half

    const _Float16* qb = qf + (long)nh*SEQ*ED;
    const char* kg = (const char*)(kf + (long)nh*SEQ*ED);   // row = 256 B
    const char* vg = (const char*)(vt + (long)nh*ED*SEQ);   // row = SEQ*2 B

    // Q fragments (B-operand): lane holds Q[qt*32+q32][e = 16j + 8*hl + i]
    f16x8 qfr[8];
    #pragma unroll
    for (int j = 0; j < 8; ++j)
        qfr[j] = *(const f16x8*)(qb + (long)(qt*32 + q32)*ED + 16*j + 8*hl);

    // cooperative stage of one 64-row K/V tile; 4 gloads per wave
    auto stage = [&](int kt, int bsel) {
        char* Kl = smem + bsel*32768;
        char* Vl = Kl + 16384;
        const char* kts = kg + (long)kt*64*256;
        const char* vts = vg + (long)kt*64*2;
        #pragma unroll
        for (int i = 0; i < 2; ++i) {                 // K rows [w*8, w*8+8)
            int row = w*8 + i*4 + (lane>>4);
            int c = (lane&15) ^ (row&15);
            gload16(kts + (long)row*256 + c*16, Kl + (w*8 + i*4)*256);
        }
        #pragma unroll
        for (int i = 0; i < 2; ++i) {                 // V rows [w*16, w*16+16)
            int row = w*16 + i*8 + (lane>>3);
            int c = (lane&7) ^ (row&7);
            gload16(vts + (long)row*(SEQ*2) + c*16, Vl + (w*16 + i*8)*128);
        }
    };

    f32x16 acc[4];
    #pragma unroll
    for (int vv = 0; vv < 4; ++vv)
      #pragma unroll
      for (int i = 0; i < 16; ++i) acc[vv][i] = 0.f;
    float mrun = -1e30f, lrun = 0.f;

    stage(0, 0);
    __syncthreads();

    const int kswz = q32 & 15;
    const int vswz = q32 & 7;

    for (int kt = 0; kt < SEQ/64; ++kt) {
        const int cur = kt & 1;
        if (kt + 1 < SEQ/64) stage(kt + 1, cur ^ 1);
        const char* Kl = smem + cur*32768;
        const char* Vl = Kl + 16384;

        // ---- QK^T: two 32x32 S^T tiles (k-rows 0-31, 32-63) ----
        f32x16 s0, s1;
        #pragma unroll
        for (int i = 0; i < 16; ++i) { s0[i] = 0.f; s1[i] = 0.f; }
        #pragma unroll
        for (int j = 0; j < 8; ++j) {
            int off = (((hl + 2*j) & 15) ^ kswz) << 4;
            f16x8 k0 = *(const f16x8*)(Kl + q32*256 + off);
            f16x8 k1 = *(const f16x8*)(Kl + 8192 + q32*256 + off);
            __builtin_amdgcn_s_setprio(1);
            s0 = __builtin_amdgcn_mfma_f32_32x32x16_f16(k0, qfr[j], s0, 0, 0, 0);
            s1 = __builtin_amdgcn_mfma_f32_32x32x16_f16(k1, qfr[j], s1, 0, 0, 0);
            __builtin_amdgcn_s_setprio(0);
        }

        // ---- online softmax (log2 domain), defer-rescale ----
        float mx = s0[0];
        #pragma unroll
        for (int i = 1; i < 16; ++i) mx = fmaxf(mx, s0[i]);
        #pragma unroll
        for (int i = 0; i < 16; ++i) mx = fmaxf(mx, s1[i]);
        mx = fmaxf(mx, __shfl_xor(mx, 32, 64));      // combine lane halves
        if (__any(mx > mrun + 11.0f)) {
            float mnew = fmaxf(mrun, mx);
            float corr = exp2f(mrun - mnew);
            lrun *= corr;
            #pragma unroll
            for (int vv = 0; vv < 4; ++vv)
                #pragma unroll
                for (int i = 0; i < 16; ++i) acc[vv][i] *= corr;
            mrun = mnew;
        }
        // P = exp2(s - mrun), packed to f16 pairs
        int wreg[2][8];
        float rsum = 0.f;
        #pragma unroll
        for (int kk = 0; kk < 2; ++kk) {
            float p[16];
            #pragma unroll
            for (int i = 0; i < 16; ++i) {
                float sv = (kk == 0) ? s0[i] : s1[i];
                p[i] = exp2f(sv - mrun);
                rsum += p[i];
            }
            #pragma unroll
            for (int tW = 0; tW < 8; ++tW)
                wreg[kk][tW] = pk2(p[2*tW], p[2*tW + 1]);
        }
        rsum += __shfl_xor(rsum, 32, 64);
        lrun += rsum;

        // ---- build PV B-operands: 2 permlane32_swap per 16-k slice ----
        f16x8 pa[4];
        #pragma unroll
        for (int kk = 0; kk < 2; ++kk) {
            #pragma unroll
            for (int par = 0; par < 2; ++par) {
                int a0 = wreg[kk][par*4 + 0], b0 = wreg[kk][par*4 + 2];
                int a1 = wreg[kk][par*4 + 1], b1 = wreg[kk][par*4 + 3];
                auto r0 = __builtin_amdgcn_permlane32_swap(a0, b0, false, false);
                auto r1 = __builtin_amdgcn_permlane32_swap(a1, b1, false, false);
                pa[kk*2 + par] = frag4(r0[0], r1[0], r0[1], r1[1]);
            }
        }

        // ---- PV: O^T += V^T · P  (4 ks slices × 4 v-subtiles) ----
        #pragma unroll
        for (int ks = 0; ks < 4; ++ks) {
            f16x8 vfr[4];
            #pragma unroll
            for (int vv = 0; vv < 4; ++vv) {
                int vrow = vv*32 + q32;
                vfr[vv] = *(const f16x8*)(Vl + vrow*128 + (((2*ks + hl) ^ vswz) << 4));
            }
            __builtin_amdgcn_s_setprio(1);
            #pragma unroll
            for (int vv = 0; vv < 4; ++vv)
                acc[vv] = __builtin_amdgcn_mfma_f32_32x32x16_f16(vfr[vv], pa[ks], acc[vv], 0, 0, 0);
            __builtin_amdgcn_s_setprio(0);
        }
        __syncthreads();   // drains vmcnt (stage kt+1 done) + protects buffers
    }

    // ---- epilogue: O^T -> ob[n][q][h*128 + v] ----
    float inv = 1.0f / lrun;
    int q = qt*32 + q32;
    long base = ((long)n*SEQ + q)*FCK + h*ED;
    #pragma unroll
    for (int vv = 0; vv < 4; ++vv) {
        #pragma unroll
        for (int rg = 0; rg < 4; ++rg) {
            f16x4 o;
            #pragma unroll
            for (int i = 0; i < 4; ++i) o[i] = (_Float16)(acc[vv][rg*4 + i] * inv);
            *(f16x4*)(ob + base + vv*32 + 8*rg + 4*hl) = o;
        }
    }
}

// ---------------------------------------------------------------------------
// Kernel 4: out[8192,1024] = ob[8192,2048](fp16) @ fc_w^T(fp16) + fc_b, fp32.
// m97-style 128x128 tile, BK=32, double-buffered LDS via global_load_lds,
// XOR chunk swizzle. 4 waves (2x2), 64x64 per wave.
// ---------------------------------------------------------------------------
__global__ __launch_bounds__(256) void fc_kernel(
    const _Float16* __restrict__ ob,
    const _Float16* __restrict__ wt,
    const float* __restrict__ fcb,
    float* __restrict__ out)
{
    __shared__ char smem[32768];            // 2 x (A 8KB + B 8KB)
    const int lane = threadIdx.x & 63;
    const int w = threadIdx.x >> 6;         // 0..3
    const int wm = w >> 1, wn = w & 1;      // 2x2 wave grid
    const int r = lane & 15, g = lane >> 4;

    const int orig = blockIdx.x;            // 512 blocks
    const int tile = ((orig & 7) << 6) | (orig >> 3);  // XCD-contiguous
    const int mt = tile >> 3;               // 0..63
    const int nt = tile & 7;                // 0..7

    const char* Ag = (const char*)(ob + (long)mt*128*FCK);
    const char* Bg = (const char*)(wt + (long)nt*128*FCK);

    auto stage = [&](int kt, int bsel) {
        char* As = smem + bsel*16384;
        char* Bs = As + 8192;
        #pragma unroll
        for (int rnd = 0; rnd < 2; ++rnd) {
            int row = rnd*64 + w*16 + (lane >> 2);
            int cs = (lane & 3) ^ ((row >> 1) & 3);
            gload16(Ag + (long)row*(FCK*2) + kt*64 + cs*16, As + rnd*4096 + w*1024);
            gload16(Bg + (long)row*(FCK*2) + kt*64 + cs*16, Bs + rnd*4096 + w*1024);
        }
    };

    f32x4 acc[4][4];
    #pragma unroll
    for (int u = 0; u < 4; ++u)
      #pragma unroll
      for (int v = 0; v < 4; ++v) acc[u][v] = (f32x4){0.f,0.f,0.f,0.f};

    stage(0, 0);
    __syncthreads();

    for (int kt = 0; kt < FCK/32; ++kt) {
        const int cur = kt & 1;
        if (kt + 1 < FCK/32) stage(kt + 1, cur ^ 1);
        const char* As = smem + cur*16384;
        const char* Bs = As + 8192;

        f16x8 afr[4], bfr[4];
        #pragma unroll
        for (int u = 0; u < 4; ++u) {
            int row = wm*64 + u*16 + r;
            afr[u] = *(const f16x8*)(As + row*64 + ((g ^ ((row >> 1) & 3)) << 4));
        }
        #pragma unroll
        for (int v = 0; v < 4; ++v) {
            int row = wn*64 + v*16 + r;
            bfr[v] = *(const f16x8*)(Bs + row*64 + ((g ^ ((row >> 1) & 3)) << 4));
        }
        __builtin_amdgcn_s_setprio(1);
        #pragma unroll
        for (int u = 0; u < 4; ++u)
          #pragma unroll
          for (int v = 0; v < 4; ++v)
            acc[u][v] = __builtin_amdgcn_mfma_f32_16x16x32_f16(afr[u], bfr[v], acc[u][v], 0, 0, 0);
        __builtin_amdgcn_s_setprio(0);
        __syncthreads();
    }

    #pragma unroll
    for (int u = 0; u < 4; ++u)
      #pragma unroll
      for (int v = 0; v < 4; ++v) {
        int col = nt*128 + wn*64 + v*16 + r;
        float bias = fcb[col];
        #pragma unroll
        for (int i = 0; i < 4; ++i) {
            int row = mt*128 + wm*64 + u*16 + 4*g + i;
            out[(long)row*EMB + col] = acc[u][v][i] + bias;
        }
      }
}

// ---------------------------------------------------------------------------
extern "C" void kernel_launch(void* const* d_in, const int* in_sizes, int n_in,
                              void* d_out, int out_size, void* d_ws, size_t ws_size,
                              hipStream_t stream) {
    const float* vals = (const float*)d_in[0];
    const float* keys = (const float*)d_in[1];
    const float* qry  = (const float*)d_in[2];
    const float* fmw  = (const float*)d_in[3];
    const float* fmb  = (const float*)d_in[4];
    const float* fcw  = (const float*)d_in[5];
    const float* fcb  = (const float*)d_in[6];
    char* ws = (char*)d_ws;
    const long SZ = 33554432L;                       // 32 MB per fp16 tensor
    _Float16* qf = (_Float16*)(ws);
    _Float16* kf = (_Float16*)(ws + SZ);
    _Float16* vf = (_Float16*)(ws + 2*SZ);
    _Float16* vt = (_Float16*)(ws + 3*SZ);
    _Float16* ob = (_Float16*)(ws + 4*SZ);
    _Float16* wt = (_Float16*)(ws + 5*SZ);           // +4 MB
    float* out = (float*)d_out;

    fmap_kernel<<<dim3(2048), dim3(256), 0, stream>>>(vals, keys, qry, fmw, fmb, qf, kf, vf);
    vtrans_kernel<<<dim3(4096), dim3(256), 0, stream>>>(vf, vt);
    cvt_kernel<<<dim3(1024), dim3(256), 0, stream>>>(fcw, wt);
    attn_kernel<<<dim3(512), dim3(512), 0, stream>>>(qf, kf, vt, ob);
    fc_kernel<<<dim3(512), dim3(256), 0, stream>>>(ob, wt, fcb, out);
}

// Round 10
// 289.381 us; speedup vs baseline: 2.7936x; 1.0274x over previous
//
#include <hip/hip_runtime.h>
#include <hip/hip_bf16.h>
#include <stdint.h>

#define N_B 4
#define SEQ 2048
#define NH 16
#define ED 128      // expanded feature dim per head
#define EMB 1024
#define FCK 2048    // NH*ED

typedef float f32x4 __attribute__((ext_vector_type(4)));
typedef float f32x16 __attribute__((ext_vector_type(16)));
typedef _Float16 f16x8 __attribute__((ext_vector_type(8)));
typedef _Float16 f16x4 __attribute__((ext_vector_type(4)));
typedef _Float16 f16x2 __attribute__((ext_vector_type(2)));
typedef __fp16 fp16v2 __attribute__((ext_vector_type(2)));

__device__ __forceinline__ void gload16(const void* g, void* l) {
    __builtin_amdgcn_global_load_lds(
        (const __attribute__((address_space(1))) uint32_t*)(g),
        (__attribute__((address_space(3))) uint32_t*)(l), 16, 0, 0);
}

__device__ __forceinline__ int pk2(float a, float b) {
    union { fp16v2 h; int i; } u;
    u.h = __builtin_amdgcn_cvt_pkrtz(a, b);
    return u.i;
}

__device__ __forceinline__ f16x2 asf16x2(int v) {
    union { int i; f16x2 h; } u; u.i = v; return u.h;
}

__device__ __forceinline__ f16x8 frag4(int d0, int d1, int d2, int d3) {
    union { int i[4]; f16x8 v; } u;
    u.i[0] = d0; u.i[1] = d1; u.i[2] = d2; u.i[3] = d3;
    return u.v;
}

#define M3(a,b,c) fmaxf(fmaxf((a),(b)),(c))

// ---------------------------------------------------------------------------
// Kernel 1: feature map. One wave per (n,s); 16 heads = 16 MFMA rows.
// z via hi/lo fp16 split of x and fm_w (3-term) -> ~fp32-accurate z.
// Outputs (all [nh][s][128] fp16): qf (scaled log2e/32), kf, vf.
// ---------------------------------------------------------------------------
__global__ __launch_bounds__(256) void fmap_kernel(
    const float* __restrict__ vals, const float* __restrict__ keys,
    const float* __restrict__ qry,  const float* __restrict__ fmw,
    const float* __restrict__ fmb,
    _Float16* __restrict__ qf, _Float16* __restrict__ kf,
    _Float16* __restrict__ vf)
{
    const int lane = threadIdx.x & 63;
    const int w = threadIdx.x >> 6;
    const int t = blockIdx.x * 4 + w;      // (n*SEQ + s)
    const int n = t >> 11;
    const int s = t & 2047;
    const int r = lane & 15;
    const int g = lane >> 4;

    f16x8 whf[4][2], wlf[4][2];
    #pragma unroll
    for (int te = 0; te < 4; ++te) {
      #pragma unroll
      for (int j = 0; j < 2; ++j) {
        const float* p = fmw + (te*16 + r)*64 + j*32 + 8*g;
        #pragma unroll
        for (int i = 0; i < 8; ++i) {
            float wv = p[i];
            _Float16 hi = (_Float16)wv;
            whf[te][j][i] = hi;
            wlf[te][j][i] = (_Float16)(wv - (float)hi);
        }
      }
    }
    float bias[4];
    #pragma unroll
    for (int te = 0; te < 4; ++te) bias[te] = fmb[te*16 + r];

    const float QSCL = 0.03125f * 1.4426950408889634f;   // (1/sqrt(1024))*log2(e)

    const long rowoff = ((long)t*16 + r) * 64;
    const float* srcs[3] = {qry, keys, vals};
    #pragma unroll
    for (int tens = 0; tens < 3; ++tens) {
        const float* src = srcs[tens] + rowoff;
        f16x8 ah[2], al[2];
        #pragma unroll
        for (int j = 0; j < 2; ++j) {
            #pragma unroll
            for (int i = 0; i < 8; ++i) {
                float x = src[j*32 + 8*g + i];
                _Float16 hi = (_Float16)x;
                ah[j][i] = hi;
                al[j][i] = (_Float16)(x - (float)hi);
            }
        }
        #pragma unroll
        for (int te = 0; te < 4; ++te) {
            f32x4 c = (f32x4){0.f,0.f,0.f,0.f};
            c = __builtin_amdgcn_mfma_f32_16x16x32_f16(ah[0], whf[te][0], c, 0, 0, 0);
            c = __builtin_amdgcn_mfma_f32_16x16x32_f16(ah[1], whf[te][1], c, 0, 0, 0);
            c = __builtin_amdgcn_mfma_f32_16x16x32_f16(ah[0], wlf[te][0], c, 0, 0, 0);
            c = __builtin_amdgcn_mfma_f32_16x16x32_f16(ah[1], wlf[te][1], c, 0, 0, 0);
            c = __builtin_amdgcn_mfma_f32_16x16x32_f16(al[0], whf[te][0], c, 0, 0, 0);
            c = __builtin_amdgcn_mfma_f32_16x16x32_f16(al[1], whf[te][1], c, 0, 0, 0);
            #pragma unroll
            for (int i = 0; i < 4; ++i) {
                float z = c[i] + bias[te];
                float ep = __expf(z), en = __expf(-z);
                int hh = 4*g + i;
                int e = te*16 + r;
                long base = (((long)n*NH + hh)*SEQ + s)*ED;
                if (tens == 0) {
                    qf[base + e]      = (_Float16)(ep * QSCL);
                    qf[base + 64 + e] = (_Float16)(en * QSCL);
                } else if (tens == 1) {
                    kf[base + e]      = (_Float16)ep;
                    kf[base + 64 + e] = (_Float16)en;
                } else {
                    vf[base + e]      = (_Float16)ep;
                    vf[base + 64 + e] = (_Float16)en;
                }
            }
        }
    }
}

// ---------------------------------------------------------------------------
// Kernel 1b: vt[nh][e][s] = vf[nh][s][e] via 64x64 LDS tiles.
// ---------------------------------------------------------------------------
__global__ __launch_bounds__(256) void vtrans_kernel(
    const _Float16* __restrict__ vf, _Float16* __restrict__ vt)
{
    __shared__ _Float16 tile[64][72];
    const int b = blockIdx.x;          // nh*64 + st*2 + et
    const int et = b & 1;
    const int st = (b >> 1) & 31;
    const int nh = b >> 6;
    const _Float16* src = vf + ((long)nh*SEQ + st*64)*ED + et*64;
    const int col4 = (threadIdx.x & 15) * 4;
    const int row0 = threadIdx.x >> 4;
    #pragma unroll
    for (int j = 0; j < 4; ++j) {
        int row = row0 + j*16;
        *(f16x4*)&tile[row][col4] = *(const f16x4*)(src + (long)row*ED + col4);
    }
    __syncthreads();
    _Float16* dst = vt + ((long)nh*ED + et*64)*SEQ + st*64;
    const int erow = threadIdx.x >> 2;
    const int sc0 = (threadIdx.x & 3) * 16;
    f16x8 o0, o1;
    #pragma unroll
    for (int i = 0; i < 8; ++i) o0[i] = tile[sc0 + i][erow];
    #pragma unroll
    for (int i = 0; i < 8; ++i) o1[i] = tile[sc0 + 8 + i][erow];
    *(f16x8*)(dst + (long)erow*SEQ + sc0) = o0;
    *(f16x8*)(dst + (long)erow*SEQ + sc0 + 8) = o1;
}

// ---------------------------------------------------------------------------
// Kernel 2: fc_w fp32 -> fp16
// ---------------------------------------------------------------------------
__global__ __launch_bounds__(256) void cvt_kernel(
    const float* __restrict__ src, _Float16* __restrict__ dst)
{
    long i = ((long)blockIdx.x*256 + threadIdx.x)*8;
    f16x8 o;
    #pragma unroll
    for (int j = 0; j < 8; ++j) o[j] = (_Float16)src[i + j];
    *(f16x8*)(dst + i) = o;
}

// ---------------------------------------------------------------------------
// Kernel 3: flash attention, 32x32 MFMA structure.
// KVBLK=128 per staged tile (two 64-col softmax passes) -> half the barriers
// and stage calls of R9. 128KB LDS double-buffer (2 x (K 32KB + V 32KB)).
// Staging addresses hoisted (kt-invariant swizzle). Packed-f16 row-sum
// (v_pk_add_f16 over the exact wreg values PV consumes; THR=8 so sum<=16K
// fits f16). max-reduce in max3 form. Sparse setprio.
// ---------------------------------------------------------------------------
__global__ __launch_bounds__(512, 2) void attn_kernel(
    const _Float16* __restrict__ qf,
    const _Float16* __restrict__ kf,
    const _Float16* __restrict__ vt,
    _Float16* __restrict__ ob)
{
    __shared__ char smem[131072];
    const int tid = threadIdx.x;
    const int lane = tid & 63;
    const int w = tid >> 6;                      // 0..7
    const int orig = blockIdx.x;                 // 512 blocks
    const int b = ((orig & 7) << 6) | (orig >> 3);  // bijective XCD swizzle
    const int nh = b >> 3;
    const int n = nh >> 4, h = nh & 15;
    const int qt = (b & 7)*8 + w;                // 0..63, 32 q-rows each
    const int q32 = lane & 31;                   // q-col / A-row index
    const int hl = lane >> 5;                    // lane half

    const _Float16* qb = qf + (long)nh*SEQ*ED;
    const char* kg = (const char*)(kf + (long)nh*SEQ*ED);   // row = 256 B
    const char* vg = (const char*)(vt + (long)nh*ED*SEQ);   // row = SEQ*2 B

    // Q fragments (B-operand): lane holds Q[qt*32+q32][e = 16j + 8*hl + i]
    f16x8 qfr[8];
    #pragma unroll
    for (int j = 0; j < 8; ++j)
        qfr[j] = *(const f16x8*)(qb + (long)(qt*32 + q32)*ED + 16*j + 8*hl);

    // hoisted staging constants (kt-invariant)
    const int srow = tid >> 4;                         // 0..31
    const int sc   = (tid & 15) ^ (srow & 15);         // XOR chunk swizzle
    const long koff = (long)srow*256  + sc*16;         // + i*8192 per round
    const long voff = (long)srow*4096 + sc*16;         // + i*131072 per round
    const int  ldst = tid*16;                          // + i*8192 per round

    // stage one 128-col K/V tile (K: 128 s-rows x 256B; V: 128 e-rows x 256B)
    auto stage = [&](int kt, int bsel) {
        char* Kl = smem + bsel*65536;
        char* Vl = Kl + 32768;
        const char* ksrc = kg + (long)kt*32768 + koff;
        const char* vsrc = vg + (long)kt*256   + voff;
        #pragma unroll
        for (int i = 0; i < 4; ++i)
            gload16(ksrc + i*8192, Kl + i*8192 + ldst);
        #pragma unroll
        for (int i = 0; i < 4; ++i)
            gload16(vsrc + (long)i*131072, Vl + i*8192 + ldst);
    };

    f32x16 acc[4];
    #pragma unroll
    for (int vv = 0; vv < 4; ++vv)
      #pragma unroll
      for (int i = 0; i < 16; ++i) acc[vv][i] = 0.f;
    float mrun = -1e30f, lrun = 0.f;

    stage(0, 0);
    __syncthreads();

    const int kswz = q32 & 15;

    for (int kt = 0; kt < SEQ/128; ++kt) {
        const int cur = kt & 1;
        if (kt + 1 < SEQ/128) stage(kt + 1, cur ^ 1);
        const char* Kl = smem + cur*65536;
        const char* Vl = Kl + 32768;

        #pragma unroll
        for (int p = 0; p < 2; ++p) {
            // ---- QK^T: two 32x32 S^T tiles (k-rows p*64+[0,32)) ----
            f32x16 s0, s1;
            #pragma unroll
            for (int i = 0; i < 16; ++i) { s0[i] = 0.f; s1[i] = 0.f; }
            const char* Kb = Kl + (p*64 + q32)*256;
            __builtin_amdgcn_s_setprio(1);
            #pragma unroll
            for (int j = 0; j < 8; ++j) {
                int off = (((hl + 2*j) & 15) ^ kswz) << 4;
                f16x8 k0 = *(const f16x8*)(Kb + off);
                f16x8 k1 = *(const f16x8*)(Kb + 8192 + off);
                s0 = __builtin_amdgcn_mfma_f32_32x32x16_f16(k0, qfr[j], s0, 0, 0, 0);
                s1 = __builtin_amdgcn_mfma_f32_32x32x16_f16(k1, qfr[j], s1, 0, 0, 0);
            }
            __builtin_amdgcn_s_setprio(0);

            // ---- online softmax (log2 domain), defer-rescale THR=8 ----
            float mx = M3(s0[0], s0[1], s0[2]);
            mx = M3(mx, s0[3], s0[4]);   mx = M3(mx, s0[5], s0[6]);
            mx = M3(mx, s0[7], s0[8]);   mx = M3(mx, s0[9], s0[10]);
            mx = M3(mx, s0[11], s0[12]); mx = M3(mx, s0[13], s0[14]);
            mx = M3(mx, s0[15], s1[0]);  mx = M3(mx, s1[1], s1[2]);
            mx = M3(mx, s1[3], s1[4]);   mx = M3(mx, s1[5], s1[6]);
            mx = M3(mx, s1[7], s1[8]);   mx = M3(mx, s1[9], s1[10]);
            mx = M3(mx, s1[11], s1[12]); mx = M3(mx, s1[13], s1[14]);
            mx = fmaxf(mx, s1[15]);
            mx = fmaxf(mx, __shfl_xor(mx, 32, 64));      // combine lane halves
            if (__any(mx > mrun + 8.0f)) {
                float mnew = fmaxf(mrun, mx);
                float corr = exp2f(mrun - mnew);
                lrun *= corr;
                #pragma unroll
                for (int vv = 0; vv < 4; ++vv)
                    #pragma unroll
                    for (int i = 0; i < 16; ++i) acc[vv][i] *= corr;
                mrun = mnew;
            }
            // P = exp2(s - mrun) packed to f16 pairs; rsum via v_pk_add_f16
            int wreg[2][8];
            f16x2 psum = (f16x2){(_Float16)0.f, (_Float16)0.f};
            #pragma unroll
            for (int kk = 0; kk < 2; ++kk) {
                #pragma unroll
                for (int tW = 0; tW < 8; ++tW) {
                    float sa = (kk == 0) ? s0[2*tW]   : s1[2*tW];
                    float sb = (kk == 0) ? s0[2*tW+1] : s1[2*tW+1];
                    int pw = pk2(exp2f(sa - mrun), exp2f(sb - mrun));
                    wreg[kk][tW] = pw;
                    psum += asf16x2(pw);
                }
            }
            float rsum = (float)psum[0] + (float)psum[1];
            rsum += __shfl_xor(rsum, 32, 64);
            lrun += rsum;

            // ---- build PV B-operands: permlane32_swap pairs ----
            f16x8 pa[4];
            #pragma unroll
            for (int kk = 0; kk < 2; ++kk) {
                #pragma unroll
                for (int par = 0; par < 2; ++par) {
                    int a0 = wreg[kk][par*4 + 0], b0 = wreg[kk][par*4 + 2];
                    int a1 = wreg[kk][par*4 + 1], b1 = wreg[kk][par*4 + 3];
                    auto r0 = __builtin_amdgcn_permlane32_swap(a0, b0, false, false);
                    auto r1 = __builtin_amdgcn_permlane32_swap(a1, b1, false, false);
                    pa[kk*2 + par] = frag4(r0[0], r1[0], r0[1], r1[1]);
                }
            }

            // ---- PV: O^T += V^T · P  (4 ks slices × 4 v-subtiles) ----
            #pragma unroll
            for (int ks = 0; ks < 4; ++ks) {
                f16x8 vfr[4];
                #pragma unroll
                for (int vv = 0; vv < 4; ++vv) {
                    int vrow = vv*32 + q32;
                    int c0 = p*8 + ks*2 + hl;
                    vfr[vv] = *(const f16x8*)(Vl + vrow*256 + ((c0 ^ kswz) << 4));
                }
                __builtin_amdgcn_s_setprio(1);
                #pragma unroll
                for (int vv = 0; vv < 4; ++vv)
                    acc[vv] = __builtin_amdgcn_mfma_f32_32x32x16_f16(vfr[vv], pa[ks], acc[vv], 0, 0, 0);
                __builtin_amdgcn_s_setprio(0);
            }
        }
        __syncthreads();   // drains vmcnt (stage kt+1 done) + protects buffers
    }

    // ---- epilogue: O^T -> ob[n][q][h*128 + v] ----
    float inv = 1.0f / lrun;
    int q = qt*32 + q32;
    long base = ((long)n*SEQ + q)*FCK + h*ED;
    #pragma unroll
    for (int vv = 0; vv < 4; ++vv) {
        #pragma unroll
        for (int rg = 0; rg < 4; ++rg) {
            f16x4 o;
            #pragma unroll
            for (int i = 0; i < 4; ++i) o[i] = (_Float16)(acc[vv][rg*4 + i] * inv);
            *(f16x4*)(ob + base + vv*32 + 8*rg + 4*hl) = o;
        }
    }
}

// ---------------------------------------------------------------------------
// Kernel 4: out[8192,1024] = ob[8192,2048](fp16) @ fc_w^T(fp16) + fc_b, fp32.
// m97-style 128x128 tile, BK=32, double-buffered LDS via global_load_lds,
// XOR chunk swizzle. 4 waves (2x2), 64x64 per wave.
// ---------------------------------------------------------------------------
__global__ __launch_bounds__(256) void fc_kernel(
    const _Float16* __restrict__ ob,
    const _Float16* __restrict__ wt,
    const float* __restrict__ fcb,
    float* __restrict__ out)
{
    __shared__ char smem[32768];            // 2 x (A 8KB + B 8KB)
    const int lane = threadIdx.x & 63;
    const int w = threadIdx.x >> 6;         // 0..3
    const int wm = w >> 1, wn = w & 1;      // 2x2 wave grid
    const int r = lane & 15, g = lane >> 4;

    const int orig = blockIdx.x;            // 512 blocks
    const int tile = ((orig & 7) << 6) | (orig >> 3);  // XCD-contiguous
    const int mt = tile >> 3;               // 0..63
    const int nt = tile & 7;                // 0..7

    const char* Ag = (const char*)(ob + (long)mt*128*FCK);
    const char* Bg = (const char*)(wt + (long)nt*128*FCK);

    auto stage = [&](int kt, int bsel) {
        char* As = smem + bsel*16384;
        char* Bs = As + 8192;
        #pragma unroll
        for (int rnd = 0; rnd < 2; ++rnd) {
            int row = rnd*64 + w*16 + (lane >> 2);
            int cs = (lane & 3) ^ ((row >> 1) & 3);
            gload16(Ag + (long)row*(FCK*2) + kt*64 + cs*16, As + rnd*4096 + w*1024);
            gload16(Bg + (long)row*(FCK*2) + kt*64 + cs*16, Bs + rnd*4096 + w*1024);
        }
    };

    f32x4 acc[4][4];
    #pragma unroll
    for (int u = 0; u < 4; ++u)
      #pragma unroll
      for (int v = 0; v < 4; ++v) acc[u][v] = (f32x4){0.f,0.f,0.f,0.f};

    stage(0, 0);
    __syncthreads();

    for (int kt = 0; kt < FCK/32; ++kt) {
        const int cur = kt & 1;
        if (kt + 1 < FCK/32) stage(kt + 1, cur ^ 1);
        const char* As = smem + cur*16384;
        const char* Bs = As + 8192;

        f16x8 afr[4], bfr[4];
        #pragma unroll
        for (int u = 0; u < 4; ++u) {
            int row = wm*64 + u*16 + r;
            afr[u] = *(const f16x8*)(As + row*64 + ((g ^ ((row >> 1) & 3)) << 4));
        }
        #pragma unroll
        for (int v = 0; v < 4; ++v) {
            int row = wn*64 + v*16 + r;
            bfr[v] = *(const f16x8*)(Bs + row*64 + ((g ^ ((row >> 1) & 3)) << 4));
        }
        __builtin_amdgcn_s_setprio(1);
        #pragma unroll
        for (int u = 0; u < 4; ++u)
          #pragma unroll
          for (int v = 0; v < 4; ++v)
            acc[u][v] = __builtin_amdgcn_mfma_f32_16x16x32_f16(afr[u], bfr[v], acc[u][v], 0, 0, 0);
        __builtin_amdgcn_s_setprio(0);
        __syncthreads();
    }

    #pragma unroll
    for (int u = 0; u < 4; ++u)
      #pragma unroll
      for (int v = 0; v < 4; ++v) {
        int col = nt*128 + wn*64 + v*16 + r;
        float bias = fcb[col];
        #pragma unroll
        for (int i = 0; i < 4; ++i) {
            int row = mt*128 + wm*64 + u*16 + 4*g + i;
            out[(long)row*EMB + col] = acc[u][v][i] + bias;
        }
      }
}

// ---------------------------------------------------------------------------
extern "C" void kernel_launch(void* const* d_in, const int* in_sizes, int n_in,
                              void* d_out, int out_size, void* d_ws, size_t ws_size,
                              hipStream_t stream) {
    const float* vals = (const float*)d_in[0];
    const float* keys = (const float*)d_in[1];
    const float* qry  = (const float*)d_in[2];
    const float* fmw  = (const float*)d_in[3];
    const float* fmb  = (const float*)d_in[4];
    const float* fcw  = (const float*)d_in[5];
    const float* fcb  = (const float*)d_in[6];
    char* ws = (char*)d_ws;
    const long SZ = 33554432L;                       // 32 MB per fp16 tensor
    _Float16* qf = (_Float16*)(ws);
    _Float16* kf = (_Float16*)(ws + SZ);
    _Float16* vf = (_Float16*)(ws + 2*SZ);
    _Float16* vt = (_Float16*)(ws + 3*SZ);
    _Float16* ob = (_Float16*)(ws + 4*SZ);
    _Float16* wt = (_Float16*)(ws + 5*SZ);           // +4 MB
    float* out = (float*)d_out;

    fmap_kernel<<<dim3(2048), dim3(256), 0, stream>>>(vals, keys, qry, fmw, fmb, qf, kf, vf);
    vtrans_kernel<<<dim3(4096), dim3(256), 0, stream>>>(vf, vt);
    cvt_kernel<<<dim3(1024), dim3(256), 0, stream>>>(fcw, wt);
    attn_kernel<<<dim3(512), dim3(512), 0, stream>>>(qf, kf, vt, ob);
    fc_kernel<<<dim3(512), dim3(256), 0, stream>>>(ob, wt, fcb, out);
}

// Round 11
// 269.938 us; speedup vs baseline: 2.9949x; 1.0720x over previous
//
#include <hip/hip_runtime.h>
#include <hip/hip_bf16.h>
#include <stdint.h>

#define N_B 4
#define SEQ 2048
#define NH 16
#define ED 128      // expanded feature dim per head
#define EMB 1024
#define FCK 2048    // NH*ED

typedef float f32x4 __attribute__((ext_vector_type(4)));
typedef float f32x16 __attribute__((ext_vector_type(16)));
typedef _Float16 f16x8 __attribute__((ext_vector_type(8)));
typedef _Float16 f16x4 __attribute__((ext_vector_type(4)));
typedef _Float16 f16x2 __attribute__((ext_vector_type(2)));
typedef __fp16 fp16v2 __attribute__((ext_vector_type(2)));

__device__ __forceinline__ void gload16(const void* g, void* l) {
    __builtin_amdgcn_global_load_lds(
        (const __attribute__((address_space(1))) uint32_t*)(g),
        (__attribute__((address_space(3))) uint32_t*)(l), 16, 0, 0);
}

__device__ __forceinline__ int pk2(float a, float b) {
    union { fp16v2 h; int i; } u;
    u.h = __builtin_amdgcn_cvt_pkrtz(a, b);
    return u.i;
}

__device__ __forceinline__ f16x2 asf16x2(int v) {
    union { int i; f16x2 h; } u; u.i = v; return u.h;
}

__device__ __forceinline__ f16x8 frag4(int d0, int d1, int d2, int d3) {
    union { int i[4]; f16x8 v; } u;
    u.i[0] = d0; u.i[1] = d1; u.i[2] = d2; u.i[3] = d3;
    return u.v;
}

// raw v_exp_f32 (inputs bounded <= 8; deep-negative -> 0 is correct)
__device__ __forceinline__ float ex2(float x) {
#if __has_builtin(__builtin_amdgcn_exp2f)
    return __builtin_amdgcn_exp2f(x);
#else
    return exp2f(x);
#endif
}

#define M3(a,b,c) fmaxf(fmaxf((a),(b)),(c))

// ---------------------------------------------------------------------------
// Kernel 1: feature map. One wave per (n,s); 16 heads = 16 MFMA rows.
// z via hi/lo fp16 split of x and fm_w (3-term) -> ~fp32-accurate z.
// Outputs (all [nh][s][128] fp16): qf (scaled log2e/32), kf, vf.
// ---------------------------------------------------------------------------
__global__ __launch_bounds__(256) void fmap_kernel(
    const float* __restrict__ vals, const float* __restrict__ keys,
    const float* __restrict__ qry,  const float* __restrict__ fmw,
    const float* __restrict__ fmb,
    _Float16* __restrict__ qf, _Float16* __restrict__ kf,
    _Float16* __restrict__ vf)
{
    const int lane = threadIdx.x & 63;
    const int w = threadIdx.x >> 6;
    const int t = blockIdx.x * 4 + w;      // (n*SEQ + s)
    const int n = t >> 11;
    const int s = t & 2047;
    const int r = lane & 15;
    const int g = lane >> 4;

    f16x8 whf[4][2], wlf[4][2];
    #pragma unroll
    for (int te = 0; te < 4; ++te) {
      #pragma unroll
      for (int j = 0; j < 2; ++j) {
        const float* p = fmw + (te*16 + r)*64 + j*32 + 8*g;
        #pragma unroll
        for (int i = 0; i < 8; ++i) {
            float wv = p[i];
            _Float16 hi = (_Float16)wv;
            whf[te][j][i] = hi;
            wlf[te][j][i] = (_Float16)(wv - (float)hi);
        }
      }
    }
    float bias[4];
    #pragma unroll
    for (int te = 0; te < 4; ++te) bias[te] = fmb[te*16 + r];

    const float QSCL = 0.03125f * 1.4426950408889634f;   // (1/sqrt(1024))*log2(e)

    const long rowoff = ((long)t*16 + r) * 64;
    const float* srcs[3] = {qry, keys, vals};
    #pragma unroll
    for (int tens = 0; tens < 3; ++tens) {
        const float* src = srcs[tens] + rowoff;
        f16x8 ah[2], al[2];
        #pragma unroll
        for (int j = 0; j < 2; ++j) {
            #pragma unroll
            for (int i = 0; i < 8; ++i) {
                float x = src[j*32 + 8*g + i];
                _Float16 hi = (_Float16)x;
                ah[j][i] = hi;
                al[j][i] = (_Float16)(x - (float)hi);
            }
        }
        #pragma unroll
        for (int te = 0; te < 4; ++te) {
            f32x4 c = (f32x4){0.f,0.f,0.f,0.f};
            c = __builtin_amdgcn_mfma_f32_16x16x32_f16(ah[0], whf[te][0], c, 0, 0, 0);
            c = __builtin_amdgcn_mfma_f32_16x16x32_f16(ah[1], whf[te][1], c, 0, 0, 0);
            c = __builtin_amdgcn_mfma_f32_16x16x32_f16(ah[0], wlf[te][0], c, 0, 0, 0);
            c = __builtin_amdgcn_mfma_f32_16x16x32_f16(ah[1], wlf[te][1], c, 0, 0, 0);
            c = __builtin_amdgcn_mfma_f32_16x16x32_f16(al[0], whf[te][0], c, 0, 0, 0);
            c = __builtin_amdgcn_mfma_f32_16x16x32_f16(al[1], whf[te][1], c, 0, 0, 0);
            #pragma unroll
            for (int i = 0; i < 4; ++i) {
                float z = c[i] + bias[te];
                float ep = __expf(z), en = __expf(-z);
                int hh = 4*g + i;
                int e = te*16 + r;
                long base = (((long)n*NH + hh)*SEQ + s)*ED;
                if (tens == 0) {
                    qf[base + e]      = (_Float16)(ep * QSCL);
                    qf[base + 64 + e] = (_Float16)(en * QSCL);
                } else if (tens == 1) {
                    kf[base + e]      = (_Float16)ep;
                    kf[base + 64 + e] = (_Float16)en;
                } else {
                    vf[base + e]      = (_Float16)ep;
                    vf[base + 64 + e] = (_Float16)en;
                }
            }
        }
    }
}

// ---------------------------------------------------------------------------
// Kernel 1b: vt[nh][e][s] = vf[nh][s][e] via 64x64 LDS tiles.
// ---------------------------------------------------------------------------
__global__ __launch_bounds__(256) void vtrans_kernel(
    const _Float16* __restrict__ vf, _Float16* __restrict__ vt)
{
    __shared__ _Float16 tile[64][72];
    const int b = blockIdx.x;          // nh*64 + st*2 + et
    const int et = b & 1;
    const int st = (b >> 1) & 31;
    const int nh = b >> 6;
    const _Float16* src = vf + ((long)nh*SEQ + st*64)*ED + et*64;
    const int col4 = (threadIdx.x & 15) * 4;
    const int row0 = threadIdx.x >> 4;
    #pragma unroll
    for (int j = 0; j < 4; ++j) {
        int row = row0 + j*16;
        *(f16x4*)&tile[row][col4] = *(const f16x4*)(src + (long)row*ED + col4);
    }
    __syncthreads();
    _Float16* dst = vt + ((long)nh*ED + et*64)*SEQ + st*64;
    const int erow = threadIdx.x >> 2;
    const int sc0 = (threadIdx.x & 3) * 16;
    f16x8 o0, o1;
    #pragma unroll
    for (int i = 0; i < 8; ++i) o0[i] = tile[sc0 + i][erow];
    #pragma unroll
    for (int i = 0; i < 8; ++i) o1[i] = tile[sc0 + 8 + i][erow];
    *(f16x8*)(dst + (long)erow*SEQ + sc0) = o0;
    *(f16x8*)(dst + (long)erow*SEQ + sc0 + 8) = o1;
}

// ---------------------------------------------------------------------------
// Kernel 2: fc_w fp32 -> fp16
// ---------------------------------------------------------------------------
__global__ __launch_bounds__(256) void cvt_kernel(
    const float* __restrict__ src, _Float16* __restrict__ dst)
{
    long i = ((long)blockIdx.x*256 + threadIdx.x)*8;
    f16x8 o;
    #pragma unroll
    for (int j = 0; j < 8; ++j) o[j] = (_Float16)src[i + j];
    *(f16x8*)(dst + i) = o;
}

// ---------------------------------------------------------------------------
// Kernel 3: flash attention, 32x32 MFMA structure, KVBLK=128.
// R11: S-tiles C-initialized to -mrun (MFMA computes s-mrun directly; saves
// 32 v_sub/pass on the common path); defer-rescale in relative form
// (scores >= 0 so mrun=0 is a valid start); raw v_exp_f32 via ex2().
// ---------------------------------------------------------------------------
__global__ __launch_bounds__(512, 2) void attn_kernel(
    const _Float16* __restrict__ qf,
    const _Float16* __restrict__ kf,
    const _Float16* __restrict__ vt,
    _Float16* __restrict__ ob)
{
    __shared__ char smem[131072];
    const int tid = threadIdx.x;
    const int lane = tid & 63;
    const int w = tid >> 6;                      // 0..7
    const int orig = blockIdx.x;                 // 512 blocks
    const int b = ((orig & 7) << 6) | (orig >> 3);  // bijective XCD swizzle
    const int nh = b >> 3;
    const int n = nh >> 4, h = nh & 15;
    const int qt = (b & 7)*8 + w;                // 0..63, 32 q-rows each
    const int q32 = lane & 31;                   // q-col / A-row index
    const int hl = lane >> 5;                    // lane half

    const _Float16* qb = qf + (long)nh*SEQ*ED;
    const char* kg = (const char*)(kf + (long)nh*SEQ*ED);   // row = 256 B
    const char* vg = (const char*)(vt + (long)nh*ED*SEQ);   // row = SEQ*2 B

    // Q fragments (B-operand): lane holds Q[qt*32+q32][e = 16j + 8*hl + i]
    f16x8 qfr[8];
    #pragma unroll
    for (int j = 0; j < 8; ++j)
        qfr[j] = *(const f16x8*)(qb + (long)(qt*32 + q32)*ED + 16*j + 8*hl);

    // hoisted staging constants (kt-invariant)
    const int srow = tid >> 4;                         // 0..31
    const int sc   = (tid & 15) ^ (srow & 15);         // XOR chunk swizzle
    const long koff = (long)srow*256  + sc*16;         // + i*8192 per round
    const long voff = (long)srow*4096 + sc*16;         // + i*131072 per round
    const int  ldst = tid*16;                          // + i*8192 per round

    // stage one 128-col K/V tile (K: 128 s-rows x 256B; V: 128 e-rows x 256B)
    auto stage = [&](int kt, int bsel) {
        char* Kl = smem + bsel*65536;
        char* Vl = Kl + 32768;
        const char* ksrc = kg + (long)kt*32768 + koff;
        const char* vsrc = vg + (long)kt*256   + voff;
        #pragma unroll
        for (int i = 0; i < 4; ++i)
            gload16(ksrc + i*8192, Kl + i*8192 + ldst);
        #pragma unroll
        for (int i = 0; i < 4; ++i)
            gload16(vsrc + (long)i*131072, Vl + i*8192 + ldst);
    };

    f32x16 acc[4];
    #pragma unroll
    for (int vv = 0; vv < 4; ++vv)
      #pragma unroll
      for (int i = 0; i < 16; ++i) acc[vv][i] = 0.f;
    float mrun = 0.f, lrun = 0.f;    // scores >= 0 (positive features)

    stage(0, 0);
    __syncthreads();

    const int kswz = q32 & 15;

    for (int kt = 0; kt < SEQ/128; ++kt) {
        const int cur = kt & 1;
        if (kt + 1 < SEQ/128) stage(kt + 1, cur ^ 1);
        const char* Kl = smem + cur*65536;
        const char* Vl = Kl + 32768;

        #pragma unroll
        for (int p = 0; p < 2; ++p) {
            // ---- QK^T: two 32x32 S^T tiles, C-init = -mrun ----
            const float nmr = -mrun;
            f32x16 s0, s1;
            #pragma unroll
            for (int i = 0; i < 16; ++i) { s0[i] = nmr; s1[i] = nmr; }
            const char* Kb = Kl + (p*64 + q32)*256;
            __builtin_amdgcn_s_setprio(1);
            #pragma unroll
            for (int j = 0; j < 8; ++j) {
                int off = (((hl + 2*j) & 15) ^ kswz) << 4;
                f16x8 k0 = *(const f16x8*)(Kb + off);
                f16x8 k1 = *(const f16x8*)(Kb + 8192 + off);
                s0 = __builtin_amdgcn_mfma_f32_32x32x16_f16(k0, qfr[j], s0, 0, 0, 0);
                s1 = __builtin_amdgcn_mfma_f32_32x32x16_f16(k1, qfr[j], s1, 0, 0, 0);
            }
            __builtin_amdgcn_s_setprio(0);

            // ---- relative max, defer-rescale THR=8 ----
            float mx = M3(s0[0], s0[1], s0[2]);
            mx = M3(mx, s0[3], s0[4]);   mx = M3(mx, s0[5], s0[6]);
            mx = M3(mx, s0[7], s0[8]);   mx = M3(mx, s0[9], s0[10]);
            mx = M3(mx, s0[11], s0[12]); mx = M3(mx, s0[13], s0[14]);
            mx = M3(mx, s0[15], s1[0]);  mx = M3(mx, s1[1], s1[2]);
            mx = M3(mx, s1[3], s1[4]);   mx = M3(mx, s1[5], s1[6]);
            mx = M3(mx, s1[7], s1[8]);   mx = M3(mx, s1[9], s1[10]);
            mx = M3(mx, s1[11], s1[12]); mx = M3(mx, s1[13], s1[14]);
            mx = fmaxf(mx, s1[15]);
            mx = fmaxf(mx, __shfl_xor(mx, 32, 64));      // combine lane halves
            if (__any(mx > 8.0f)) {                       // rare path
                float d = fmaxf(mx, 0.f);
                float corr = ex2(-d);
                mrun += d;
                lrun *= corr;
                #pragma unroll
                for (int vv = 0; vv < 4; ++vv)
                    #pragma unroll
                    for (int i = 0; i < 16; ++i) acc[vv][i] *= corr;
                #pragma unroll
                for (int i = 0; i < 16; ++i) { s0[i] -= d; s1[i] -= d; }
            }
            // P = exp2(s_rel); rsum via packed f16 adds
            int wreg[2][8];
            f16x2 psum = (f16x2){(_Float16)0.f, (_Float16)0.f};
            #pragma unroll
            for (int kk = 0; kk < 2; ++kk) {
                #pragma unroll
                for (int tW = 0; tW < 8; ++tW) {
                    float sa = (kk == 0) ? s0[2*tW]   : s1[2*tW];
                    float sb = (kk == 0) ? s0[2*tW+1] : s1[2*tW+1];
                    int pw = pk2(ex2(sa), ex2(sb));
                    wreg[kk][tW] = pw;
                    psum += asf16x2(pw);
                }
            }
            float rsum = (float)psum[0] + (float)psum[1];
            rsum += __shfl_xor(rsum, 32, 64);
            lrun += rsum;

            // ---- build PV B-operands: permlane32_swap pairs ----
            f16x8 pa[4];
            #pragma unroll
            for (int kk = 0; kk < 2; ++kk) {
                #pragma unroll
                for (int par = 0; par < 2; ++par) {
                    int a0 = wreg[kk][par*4 + 0], b0 = wreg[kk][par*4 + 2];
                    int a1 = wreg[kk][par*4 + 1], b1 = wreg[kk][par*4 + 3];
                    auto r0 = __builtin_amdgcn_permlane32_swap(a0, b0, false, false);
                    auto r1 = __builtin_amdgcn_permlane32_swap(a1, b1, false, false);
                    pa[kk*2 + par] = frag4(r0[0], r1[0], r0[1], r1[1]);
                }
            }

            // ---- PV: O^T += V^T · P  (4 ks slices × 4 v-subtiles) ----
            #pragma unroll
            for (int ks = 0; ks < 4; ++ks) {
                f16x8 vfr[4];
                #pragma unroll
                for (int vv = 0; vv < 4; ++vv) {
                    int vrow = vv*32 + q32;
                    int c0 = p*8 + ks*2 + hl;
                    vfr[vv] = *(const f16x8*)(Vl + vrow*256 + ((c0 ^ kswz) << 4));
                }
                __builtin_amdgcn_s_setprio(1);
                #pragma unroll
                for (int vv = 0; vv < 4; ++vv)
                    acc[vv] = __builtin_amdgcn_mfma_f32_32x32x16_f16(vfr[vv], pa[ks], acc[vv], 0, 0, 0);
                __builtin_amdgcn_s_setprio(0);
            }
        }
        __syncthreads();   // drains vmcnt (stage kt+1 done) + protects buffers
    }

    // ---- epilogue: O^T -> ob[n][q][h*128 + v] ----
    float inv = 1.0f / lrun;
    int q = qt*32 + q32;
    long base = ((long)n*SEQ + q)*FCK + h*ED;
    #pragma unroll
    for (int vv = 0; vv < 4; ++vv) {
        #pragma unroll
        for (int rg = 0; rg < 4; ++rg) {
            f16x4 o;
            #pragma unroll
            for (int i = 0; i < 4; ++i) o[i] = (_Float16)(acc[vv][rg*4 + i] * inv);
            *(f16x4*)(ob + base + vv*32 + 8*rg + 4*hl) = o;
        }
    }
}

// ---------------------------------------------------------------------------
// Kernel 4: out[8192,1024] = ob[8192,2048](fp16) @ fc_w^T(fp16) + fc_b, fp32.
// m97-style 128x128 tile, BK=32, double-buffered LDS via global_load_lds,
// XOR chunk swizzle. 4 waves (2x2), 64x64 per wave.
// ---------------------------------------------------------------------------
__global__ __launch_bounds__(256) void fc_kernel(
    const _Float16* __restrict__ ob,
    const _Float16* __restrict__ wt,
    const float* __restrict__ fcb,
    float* __restrict__ out)
{
    __shared__ char smem[32768];            // 2 x (A 8KB + B 8KB)
    const int lane = threadIdx.x & 63;
    const int w = threadIdx.x >> 6;         // 0..3
    const int wm = w >> 1, wn = w & 1;      // 2x2 wave grid
    const int r = lane & 15, g = lane >> 4;

    const int orig = blockIdx.x;            // 512 blocks
    const int tile = ((orig & 7) << 6) | (orig >> 3);  // XCD-contiguous
    const int mt = tile >> 3;               // 0..63
    const int nt = tile & 7;                // 0..7

    const char* Ag = (const char*)(ob + (long)mt*128*FCK);
    const char* Bg = (const char*)(wt + (long)nt*128*FCK);

    auto stage = [&](int kt, int bsel) {
        char* As = smem + bsel*16384;
        char* Bs = As + 8192;
        #pragma unroll
        for (int rnd = 0; rnd < 2; ++rnd) {
            int row = rnd*64 + w*16 + (lane >> 2);
            int cs = (lane & 3) ^ ((row >> 1) & 3);
            gload16(Ag + (long)row*(FCK*2) + kt*64 + cs*16, As + rnd*4096 + w*1024);
            gload16(Bg + (long)row*(FCK*2) + kt*64 + cs*16, Bs + rnd*4096 + w*1024);
        }
    };

    f32x4 acc[4][4];
    #pragma unroll
    for (int u = 0; u < 4; ++u)
      #pragma unroll
      for (int v = 0; v < 4; ++v) acc[u][v] = (f32x4){0.f,0.f,0.f,0.f};

    stage(0, 0);
    __syncthreads();

    for (int kt = 0; kt < FCK/32; ++kt) {
        const int cur = kt & 1;
        if (kt + 1 < FCK/32) stage(kt + 1, cur ^ 1);
        const char* As = smem + cur*16384;
        const char* Bs = As + 8192;

        f16x8 afr[4], bfr[4];
        #pragma unroll
        for (int u = 0; u < 4; ++u) {
            int row = wm*64 + u*16 + r;
            afr[u] = *(const f16x8*)(As + row*64 + ((g ^ ((row >> 1) & 3)) << 4));
        }
        #pragma unroll
        for (int v = 0; v < 4; ++v) {
            int row = wn*64 + v*16 + r;
            bfr[v] = *(const f16x8*)(Bs + row*64 + ((g ^ ((row >> 1) & 3)) << 4));
        }
        __builtin_amdgcn_s_setprio(1);
        #pragma unroll
        for (int u = 0; u < 4; ++u)
          #pragma unroll
          for (int v = 0; v < 4; ++v)
            acc[u][v] = __builtin_amdgcn_mfma_f32_16x16x32_f16(afr[u], bfr[v], acc[u][v], 0, 0, 0);
        __builtin_amdgcn_s_setprio(0);
        __syncthreads();
    }

    #pragma unroll
    for (int u = 0; u < 4; ++u)
      #pragma unroll
      for (int v = 0; v < 4; ++v) {
        int col = nt*128 + wn*64 + v*16 + r;
        float bias = fcb[col];
        #pragma unroll
        for (int i = 0; i < 4; ++i) {
            int row = mt*128 + wm*64 + u*16 + 4*g + i;
            out[(long)row*EMB + col] = acc[u][v][i] + bias;
        }
      }
}

// ---------------------------------------------------------------------------
extern "C" void kernel_launch(void* const* d_in, const int* in_sizes, int n_in,
                              void* d_out, int out_size, void* d_ws, size_t ws_size,
                              hipStream_t stream) {
    const float* vals = (const float*)d_in[0];
    const float* keys = (const float*)d_in[1];
    const float* qry  = (const float*)d_in[2];
    const float* fmw  = (const float*)d_in[3];
    const float* fmb  = (const float*)d_in[4];
    const float* fcw  = (const float*)d_in[5];
    const float* fcb  = (const float*)d_in[6];
    char* ws = (char*)d_ws;
    const long SZ = 33554432L;                       // 32 MB per fp16 tensor
    _Float16* qf = (_Float16*)(ws);
    _Float16* kf = (_Float16*)(ws + SZ);
    _Float16* vf = (_Float16*)(ws + 2*SZ);
    _Float16* vt = (_Float16*)(ws + 3*SZ);
    _Float16* ob = (_Float16*)(ws + 4*SZ);
    _Float16* wt = (_Float16*)(ws + 5*SZ);           // +4 MB
    float* out = (float*)d_out;

    fmap_kernel<<<dim3(2048), dim3(256), 0, stream>>>(vals, keys, qry, fmw, fmb, qf, kf, vf);
    vtrans_kernel<<<dim3(4096), dim3(256), 0, stream>>>(vf, vt);
    cvt_kernel<<<dim3(1024), dim3(256), 0, stream>>>(fcw, wt);
    attn_kernel<<<dim3(512), dim3(512), 0, stream>>>(qf, kf, vt, ob);
    fc_kernel<<<dim3(512), dim3(256), 0, stream>>>(ob, wt, fcb, out);
}